// Round 6
// baseline (1842.740 us; speedup 1.0000x reference)
//
#include <hip/hip_runtime.h>
#include <stdint.h>

// GraFormer forward, MI355X gfx950.
// x (residual) kept fp32 in d_out, updated in place by GEMM epilogues.
// All GEMM operands bf16 (MFMA 16x16x32), fp32 accumulate.
// R1/R2: m97 LDS-staged GEMM. R3: depth-2 pipeline + XCD swizzle + fusions.
// R4/R5: attn d-split + block-per-batch-elem LDS staging.
// R6: GEMM rewritten single-shot: whole K=256 panel of A and B staged to LDS
//     (64KB+64KB) in one burst of 32 gload_lds per wave -> ONE vmcnt(0) wait
//     per block instead of 8 exposed round-trips (K=256 has only 8 K-steps;
//     rolling pipelines never reach steady state -> R3/R5 GEMMs sat at 2800
//     cyc/step with MfmaUtil 3.5%). K=512 runs two phases. slot^(row&7)
//     swizzle on global source + ds_read side -> conflict-free reads.

#define BATCH 4096
#define NJ 17
#define NHEAD 8

typedef __bf16 bf16x8 __attribute__((ext_vector_type(8)));
typedef float f32x4 __attribute__((ext_vector_type(4)));

__device__ __forceinline__ float bf2f(unsigned short u){
  union { unsigned int i; float f; } v; v.i = ((unsigned int)u) << 16; return v.f;
}
__device__ __forceinline__ unsigned short f2bf(float f){
  union { float f; unsigned int i; } v; v.f = f;
  unsigned int i = v.i;
  return (unsigned short)((i + 0x7fffu + ((i >> 16) & 1u)) >> 16);
}
__device__ __forceinline__ float blo(unsigned int v){ union{unsigned int i;float f;}x; x.i=v<<16; return x.f; }
__device__ __forceinline__ float bhi(unsigned int v){ union{unsigned int i;float f;}x; x.i=v&0xffff0000u; return x.f; }

__device__ __forceinline__ void gload_lds16(const void* g, void* l) {
  __builtin_amdgcn_global_load_lds(
      (const __attribute__((address_space(1))) unsigned int*)g,
      (__attribute__((address_space(3))) unsigned int*)l, 16, 0, 0);
}

// ---------------- prep: pre_3d -> bf16, silu(c) -> bf16 (per chunk) ----------------
__global__ __launch_bounds__(256) void prep_kernel(
    const float* __restrict__ pre, const float* __restrict__ c,
    unsigned short* __restrict__ pre_bf, unsigned short* __restrict__ silc_bf)
{
  size_t i = (size_t)(blockIdx.x*256 + threadIdx.x)*4;
  float4 p = *(const float4*)(pre + i);
  float4 cv = *(const float4*)(c + i);
  float s0 = cv.x/(1.f+__expf(-cv.x));
  float s1 = cv.y/(1.f+__expf(-cv.y));
  float s2 = cv.z/(1.f+__expf(-cv.z));
  float s3 = cv.w/(1.f+__expf(-cv.w));
  uint2 po, so;
  po.x = (unsigned)f2bf(p.x) | ((unsigned)f2bf(p.y)<<16);
  po.y = (unsigned)f2bf(p.z) | ((unsigned)f2bf(p.w)<<16);
  so.x = (unsigned)f2bf(s0) | ((unsigned)f2bf(s1)<<16);
  so.y = (unsigned)f2bf(s2) | ((unsigned)f2bf(s3)<<16);
  *(uint2*)(pre_bf + i) = po;
  *(uint2*)(silc_bf + i) = so;
}

// ---------------- batched weight transpose+convert: dst[n*K+k] = bf16(src[k*N+n]) ----
struct TJob { const float* src; unsigned short* dst; int K; int N; };
struct TJobs { TJob j[22]; };

__global__ __launch_bounds__(256) void transpose_kernel(TJobs jobs)
{
  TJob jb = jobs.j[blockIdx.y];
  int total = jb.K * jb.N;
  int idx = blockIdx.x*256 + threadIdx.x;
  if (idx >= total) return;
  int n = idx / jb.K;
  int k = idx - n*jb.K;
  jb.dst[idx] = f2bf(jb.src[(size_t)k*jb.N + n]);
}

// ---------------- Lm = dh[:,None]*A*dh[None,:], dh=(colsum+1e-5)^-0.5 -----------
__global__ void lm_kernel(const float* __restrict__ A_hat, float* __restrict__ LmOut)
{
  int L = blockIdx.x;
  const float* a = A_hat + L*289;
  float* Lm = LmOut + L*289;
  __shared__ float dh[17];
  int t = threadIdx.x;
  if (t < 17) {
    float s = 0;
    for (int i = 0; i < 17; i++) s += a[i*17 + t];
    dh[t] = 1.0f/sqrtf(s + 1e-5f);
  }
  __syncthreads();
  for (int i = t; i < 289; i += 64) {
    int qq = i/17, jj = i - qq*17;
    Lm[i] = dh[qq]*a[i]*dh[jj];
  }
}

// ---- custom-LN (unbiased std, eps added to std) + adaLN modulate ----
// shsc: [rows, 512] bf16 (sh = cols 0-255, sc = cols 256-511)
__global__ __launch_bounds__(256) void lnmod_kernel(
    const float* __restrict__ x, const unsigned short* __restrict__ shsc,
    const float* __restrict__ g, const float* __restrict__ b,
    unsigned short* __restrict__ out)
{
  int row = blockIdx.x*4 + (threadIdx.x>>6);
  int lane = threadIdx.x & 63;
  const float4 v = *(const float4*)(x + (size_t)row*256 + lane*4);
  float s = v.x+v.y+v.z+v.w;
#pragma unroll
  for (int o=32;o;o>>=1) s += __shfl_down(s,o,64);
  float mu = __shfl(s,0,64) * (1.f/256.f);
  float d0=v.x-mu,d1=v.y-mu,d2=v.z-mu,d3=v.w-mu;
  float qq = d0*d0+d1*d1+d2*d2+d3*d3;
#pragma unroll
  for (int o=32;o;o>>=1) qq += __shfl_down(qq,o,64);
  qq = __shfl(qq,0,64);
  float rstd = 1.f/(sqrtf(qq*(1.f/255.f)) + 1e-6f);
  int c = lane*4;
  const float4 gv = *(const float4*)(g + c);
  const float4 bv = *(const float4*)(b + c);
  const uint2 shp = *(const uint2*)(shsc + (size_t)row*512 + c);
  const uint2 scp = *(const uint2*)(shsc + (size_t)row*512 + 256 + c);
  float o0 = (gv.x*d0*rstd + bv.x)*(1.f+blo(scp.x)) + blo(shp.x);
  float o1 = (gv.y*d1*rstd + bv.y)*(1.f+bhi(scp.x)) + bhi(shp.x);
  float o2 = (gv.z*d2*rstd + bv.z)*(1.f+blo(scp.y)) + blo(shp.y);
  float o3 = (gv.w*d3*rstd + bv.w)*(1.f+bhi(scp.y)) + bhi(shp.y);
  uint2 ov;
  ov.x = (unsigned)f2bf(o0) | ((unsigned)f2bf(o1)<<16);
  ov.y = (unsigned)f2bf(o2) | ((unsigned)f2bf(o3)<<16);
  *(uint2*)(out + (size_t)row*256 + c) = ov;
}

// ---------------- standard LN (biased var, eps in sqrt) + relu, in place, bf16 ----
template<int C>
__global__ __launch_bounds__(256) void lnstd_relu_kernel(
    unsigned short* __restrict__ io, const float* __restrict__ g, const float* __restrict__ b)
{
  constexpr int EPL = C/64;
  int row = blockIdx.x*4 + (threadIdx.x>>6);
  int lane = threadIdx.x & 63;
  unsigned short* rp = io + (size_t)row*C + lane*EPL;
  float v[EPL];
  if constexpr (EPL == 2) { unsigned int u = *(const unsigned int*)rp; v[0]=blo(u); v[1]=bhi(u); }
  else { v[0] = bf2f(rp[0]); }
  float s = 0;
#pragma unroll
  for (int e=0;e<EPL;e++) s += v[e];
#pragma unroll
  for (int o=32;o;o>>=1) s += __shfl_down(s,o,64);
  float mu = __shfl(s,0,64) * (1.f/C);
  float qq = 0;
#pragma unroll
  for (int e=0;e<EPL;e++){ float d=v[e]-mu; qq += d*d; }
#pragma unroll
  for (int o=32;o;o>>=1) qq += __shfl_down(qq,o,64);
  qq = __shfl(qq,0,64);
  float rstd = rsqrtf(qq*(1.f/C) + 1e-5f);
  unsigned short ov[EPL];
#pragma unroll
  for (int e=0;e<EPL;e++){
    int ccol = lane*EPL + e;
    float o = fmaxf(g[ccol]*(v[e]-mu)*rstd + b[ccol], 0.f);
    ov[e] = f2bf(o);
  }
  if constexpr (EPL==2){ *(unsigned int*)rp = (unsigned)ov[0] | ((unsigned)ov[1]<<16); }
  else rp[0] = ov[0];
}

// ---------------- skel = base_mask + sigmoid(jf2 @ jrp_w + jrp_b)*dyn_scale ------
__global__ __launch_bounds__(256) void skel_kernel(
    const unsigned short* __restrict__ jf2, const unsigned short* __restrict__ jrpt,
    const float* __restrict__ jrp_b,
    const float* __restrict__ dwp, const float* __restrict__ swp,
    const float* __restrict__ cwp, const float* __restrict__ dsp,
    float* __restrict__ skel)
{
  int gid = blockIdx.x*256 + threadIdx.x;
  int row = gid / 17;
  int k = gid - row*17;
  int q = row % 17;
  const uint4* a = (const uint4*)(jf2 + (size_t)row*64);
  const uint4* w = (const uint4*)(jrpt + k*64);
  float acc = jrp_b[k];
#pragma unroll
  for (int c = 0; c < 8; c++) {
    uint4 ua = a[c], uw = w[c];
    acc += blo(ua.x)*blo(uw.x) + bhi(ua.x)*bhi(uw.x)
         + blo(ua.y)*blo(uw.y) + bhi(ua.y)*bhi(uw.y)
         + blo(ua.z)*blo(uw.z) + bhi(ua.z)*bhi(uw.z)
         + blo(ua.w)*blo(uw.w) + bhi(ua.w)*bhi(uw.w);
  }
  float sig = 1.f/(1.f + __expf(-acc));
  float base = 1.f;
  const int dqa[16] = {0,1,2,0,4,5,0,7,8,9,8,11,12,8,14,15};
  const int dka[16] = {1,2,3,4,5,6,7,8,9,10,11,12,13,14,15,16};
#pragma unroll
  for (int t = 0; t < 16; t++) if (q==dqa[t] && k==dka[t]) base += dwp[0];
  const int s0a[6] = {1,2,3,11,12,13};
  const int s1a[6] = {4,5,6,14,15,16};
#pragma unroll
  for (int t = 0; t < 6; t++) if ((q==s0a[t]&&k==s1a[t])||(q==s1a[t]&&k==s0a[t])) base += swp[0];
  if (q==k) base += cwp[0];
  skel[gid] = base + sig*dsp[0];
}

// ---------------- attention: block per batch elem, KV/skel/mask in LDS ----------
// KV: [rows][512] bf16, K = cols 0-255, V = cols 256-511.
// 320 threads (5 waves); threads 0..271 active: pair (2t,2t+1) shares one
// (h,q), 16 dims each; partial QK dots combined via __shfl_xor(.,1).
__device__ __forceinline__ void load16f(const unsigned short* p, float* f){
  const uint4* p4 = (const uint4*)p;
#pragma unroll
  for (int c=0;c<2;c++){
    uint4 u=p4[c];
    f[c*8+0]=blo(u.x); f[c*8+1]=bhi(u.x); f[c*8+2]=blo(u.y); f[c*8+3]=bhi(u.y);
    f[c*8+4]=blo(u.z); f[c*8+5]=bhi(u.z); f[c*8+6]=blo(u.w); f[c*8+7]=bhi(u.w);
  }
}

__global__ __launch_bounds__(320) void attn_kernel(
    const unsigned short* Q, const unsigned short* __restrict__ KV,
    const float* __restrict__ skel,
    const int* __restrict__ mask, unsigned short* att)
{
  __shared__ unsigned short kvs[17*512];   // 17408 B
  __shared__ float sks[289];
  __shared__ int   mks[289];
  const int b = blockIdx.x;
  const int tid = threadIdx.x;

  const uint4* src = (const uint4*)(KV + (size_t)b*17*512);
  for (int i = tid; i < 1088; i += 320) ((uint4*)kvs)[i] = src[i];
  const float* skb = skel + (size_t)b*289;
  const int* mkb = mask + (size_t)b*289;
  for (int i = tid; i < 289; i += 320) { sks[i] = skb[i]; mks[i] = mkb[i]; }
  __syncthreads();
  if (tid >= 272) return;

  const int t2 = tid >> 1;            // (h,q) work item, 0..135
  const int dh = tid & 1;             // d-half
  const int h = t2 / 17;
  const int q = t2 - h*17;
  const int col = h*32 + dh*16;       // column offset within a KV row (shorts)
  size_t rq = ((size_t)(b*17+q))*256 + col;
  float qv[16];
  load16f(Q + rq, qv);

  float p[17];
  float mx = -3e38f;
#pragma unroll
  for (int k = 0; k < 17; k++) {
    const uint4* kp = (const uint4*)(kvs + k*512 + col);
    float s = 0;
#pragma unroll
    for (int c = 0; c < 2; c++) {
      uint4 u = kp[c];
      s += qv[c*8+0]*blo(u.x) + qv[c*8+1]*bhi(u.x)
         + qv[c*8+2]*blo(u.y) + qv[c*8+3]*bhi(u.y)
         + qv[c*8+4]*blo(u.z) + qv[c*8+5]*bhi(u.z)
         + qv[c*8+6]*blo(u.w) + qv[c*8+7]*bhi(u.w);
    }
    s += __shfl_xor(s, 1, 64);        // combine the two d-halves
    s *= 0.17677669529663687f;        // 1/sqrt(32)
    float gvl = (mks[q*17+k]==0) ? -1e9f : s*sks[q*17+k];
    p[k] = gvl;
    mx = fmaxf(mx, gvl);
  }
  float sum = 0;
#pragma unroll
  for (int k = 0; k < 17; k++){ p[k] = __expf(p[k]-mx); sum += p[k]; }
  float inv = 1.f/sum;
  float acc[16];
#pragma unroll
  for (int d=0; d<16; d++) acc[d]=0;
#pragma unroll
  for (int k = 0; k < 17; k++) {
    float pk = p[k]*inv;
    const uint4* vp = (const uint4*)(kvs + k*512 + 256 + col);
#pragma unroll
    for (int c=0;c<2;c++){
      uint4 u=vp[c];
      acc[c*8+0] += pk*blo(u.x); acc[c*8+1] += pk*bhi(u.x);
      acc[c*8+2] += pk*blo(u.y); acc[c*8+3] += pk*bhi(u.y);
      acc[c*8+4] += pk*blo(u.z); acc[c*8+5] += pk*bhi(u.z);
      acc[c*8+6] += pk*blo(u.w); acc[c*8+7] += pk*bhi(u.w);
    }
  }
  uint4 o[2];
#pragma unroll
  for (int c=0;c<2;c++){
    o[c].x = (unsigned)f2bf(acc[c*8+0]) | ((unsigned)f2bf(acc[c*8+1])<<16);
    o[c].y = (unsigned)f2bf(acc[c*8+2]) | ((unsigned)f2bf(acc[c*8+3])<<16);
    o[c].z = (unsigned)f2bf(acc[c*8+4]) | ((unsigned)f2bf(acc[c*8+5])<<16);
    o[c].w = (unsigned)f2bf(acc[c*8+6]) | ((unsigned)f2bf(acc[c*8+7])<<16);
  }
  uint4* op = (uint4*)(att + rq);
  op[0] = o[0]; op[1] = o[1];
}

// ---------------- Lm @ y per batch-elem, in place (17xD), D = 256 or 512 ---------
template<int D>
__global__ __launch_bounds__(256) void lmapply_kernel(
    unsigned short* __restrict__ io, const float* __restrict__ Lm)
{
  __shared__ unsigned short ys[17*D];
  __shared__ float lms[289];
  int b = blockIdx.x;
  int tid = threadIdx.x;
  unsigned short* base = io + (size_t)b*17*D;
  constexpr int CH = 17*D/8;
  for (int i = tid; i < CH; i += 256) ((uint4*)ys)[i] = ((const uint4*)base)[i];
  for (int i = tid; i < 289; i += 256) lms[i] = Lm[i];
  __syncthreads();
#pragma unroll
  for (int c0 = 0; c0 < D; c0 += 256) {
    int c = c0 + tid;
    float yv[17];
#pragma unroll
    for (int j = 0; j < 17; j++) yv[j] = bf2f(ys[j*D + c]);
#pragma unroll
    for (int qi = 0; qi < 17; qi++) {
      float a = 0;
#pragma unroll
      for (int j = 0; j < 17; j++) a += lms[qi*17+j]*yv[j];
      base[qi*D + c] = f2bf(a);
    }
  }
}

// ---------------- small GEMM (register-direct, kept for N=64): ------------------
template<int TM, int TN, int EPI>
__global__ __launch_bounds__(256) void gemm_kernel(
    const unsigned short* __restrict__ A, const unsigned short* __restrict__ Bt,
    const float* __restrict__ bias, unsigned short* __restrict__ outbf,
    float* __restrict__ x_io, const unsigned short* __restrict__ gt,
    int N, int K)
{
  int lane = threadIdx.x & 63;
  int wave = threadIdx.x >> 6;
  int lm = lane & 15, quad = lane >> 4;
  int wm0 = blockIdx.x*(2*TM*16) + (wave>>1)*(TM*16);
  int wn0 = blockIdx.y*(2*TN*16) + (wave&1)*(TN*16);
  const unsigned short* pa[TM];
  const unsigned short* pb[TN];
#pragma unroll
  for (int t=0;t<TM;t++) pa[t] = A + (size_t)(wm0 + t*16 + lm)*K + quad*8;
#pragma unroll
  for (int t=0;t<TN;t++) pb[t] = Bt + (size_t)(wn0 + t*16 + lm)*K + quad*8;
  f32x4 acc[TM][TN] = {};
  for (int kc = 0; kc < K; kc += 32) {
    bf16x8 af[TM], bfv[TN];
#pragma unroll
    for (int t=0;t<TM;t++) af[t] = *(const bf16x8*)(pa[t] + kc);
#pragma unroll
    for (int t=0;t<TN;t++) bfv[t] = *(const bf16x8*)(pb[t] + kc);
#pragma unroll
    for (int i=0;i<TM;i++)
#pragma unroll
      for (int j=0;j<TN;j++)
        acc[i][j] = __builtin_amdgcn_mfma_f32_16x16x32_bf16(af[i], bfv[j], acc[i][j], 0, 0, 0);
  }
#pragma unroll
  for (int j=0;j<TN;j++) {
    int col = wn0 + j*16 + lm;
    float bv = bias[col];
#pragma unroll
    for (int i=0;i<TM;i++) {
      int r0 = wm0 + i*16 + quad*4;
#pragma unroll
      for (int e=0;e<4;e++) {
        int rr = r0 + e;
        float v = acc[i][j][e] + bv;
        if (EPI == 0) {
          outbf[(size_t)rr*N + col] = f2bf(v);
        } else if (EPI == 1) {
          outbf[(size_t)rr*N + col] = f2bf(fmaxf(v, 0.f));
        } else {
          size_t xi = (size_t)rr*N + col;
          x_io[xi] += bf2f(gt[(size_t)rr*256 + col]) * v;
        }
      }
    }
  }
}

// ---------------- main GEMM: single-shot K-resident, 128x128 tile ---------------
// grid = (N/128, M/128), XCD-bijective remap (A-panel L2 reuse).
// Per 256-wide K-phase: whole A panel (128x256 bf16 = 64KB) and B panel (64KB)
// staged to LDS with 32 gload_lds per wave issued back-to-back (max MLP), one
// __syncthreads() (vmcnt(0)+barrier), then 8 k-steps of ds_read+MFMA with no
// further syncs. K=512 runs two phases (acc carried). 1 block/CU (128KB LDS).
// LDS layout: row stride 256 shorts; physical 16B slot p of row r holds global
// slot p^(r&7) (pre-swizzled global source; same XOR on ds_read side) ->
// stage instrs still fetch full contiguous 512B rows; reads conflict-free.
// EPI: 0 = store bf16 (optional split at splitN -> out2), 1 = relu store,
//      3 = x_io += bf2f(gt)*val (N=256 fixed).
template<int EPI>
__global__ __launch_bounds__(256) void gemm_lds_kernel(
    const unsigned short* __restrict__ A, const unsigned short* __restrict__ Bt,
    const float* __restrict__ bias, const float* __restrict__ bias2,
    unsigned short* __restrict__ out1, int ld1,
    unsigned short* __restrict__ out2, int ld2, int splitN,
    float* __restrict__ x_io, const unsigned short* __restrict__ gt,
    int K)
{
  __shared__ unsigned short As[128*256];   // 64 KB
  __shared__ unsigned short Bs[128*256];   // 64 KB
  const int tid = threadIdx.x;
  const int lane = tid & 63;
  const int wave = tid >> 6;
  const int lm = lane & 15, quad = lane >> 4;

  // bijective XCD remap: flat -> wg such that each XCD owns a contiguous range
  const int gx = gridDim.x;
  const int nwg = gx * (int)gridDim.y;
  int flat = (int)blockIdx.y * gx + (int)blockIdx.x;
  int xcd = flat & 7, idx = flat >> 3;
  int qd = nwg >> 3, rm = nwg & 7;
  int wg = (xcd < rm ? xcd*(qd+1) : rm*(qd+1) + (xcd-rm)*qd) + idx;
  int by = wg / gx, bx = wg - by*gx;
  const int m0 = by * 128;
  const int n0 = bx * 128;
  const int wm = (wave >> 1) * 64;
  const int wn = (wave & 1) * 64;

  const int l5 = lane >> 5;           // row parity within a 1KB stage instr
  const int ls = lane & 31;           // physical 16B slot within row

  f32x4 acc[4][4] = {};

  for (int kc = 0; kc < K; kc += 256) {
    if (kc) __syncthreads();          // all waves done reading previous phase
    // stage whole 128x256 A and B panels: 16+16 gload_lds per wave
#pragma unroll
    for (int i = 0; i < 16; i++) {
      int id2 = wave*16 + i;          // 0..63 -> 2 rows each
      int row = id2*2 + l5;           // 0..127
      int slot = ls ^ (row & 7);      // pre-swizzled global slot
      gload_lds16(A  + (size_t)(m0 + row)*K + kc + slot*8, As + id2*512 + lane*8);
      gload_lds16(Bt + (size_t)(n0 + row)*K + kc + slot*8, Bs + id2*512 + lane*8);
    }
    __syncthreads();                  // drains vmcnt(0): panels resident

#pragma unroll
    for (int k2 = 0; k2 < 8; k2++) {
      bf16x8 af[4], bfv[4];
#pragma unroll
      for (int t = 0; t < 4; t++) {
        int ra = wm + t*16 + lm;
        af[t]  = *(const bf16x8*)(As + ra*256 + ((((k2<<2)|quad) ^ (ra & 7)) << 3));
        int rb = wn + t*16 + lm;
        bfv[t] = *(const bf16x8*)(Bs + rb*256 + ((((k2<<2)|quad) ^ (rb & 7)) << 3));
      }
#pragma unroll
      for (int i = 0; i < 4; i++)
#pragma unroll
        for (int j = 0; j < 4; j++)
          acc[i][j] = __builtin_amdgcn_mfma_f32_16x16x32_bf16(af[i], bfv[j], acc[i][j], 0, 0, 0);
    }
  }

#pragma unroll
  for (int j = 0; j < 4; j++) {
    int col = n0 + wn + j*16 + lm;
    float bv = (bias2 && col >= splitN) ? bias2[col - splitN] : bias[col];
#pragma unroll
    for (int i = 0; i < 4; i++) {
      int r0 = m0 + wm + i*16 + quad*4;
#pragma unroll
      for (int e = 0; e < 4; e++) {
        int rr = r0 + e;
        float v = acc[i][j][e] + bv;
        if (EPI == 0) {
          if (out2 && col >= splitN) out2[(size_t)rr*ld2 + (col - splitN)] = f2bf(v);
          else                       out1[(size_t)rr*ld1 + col] = f2bf(v);
        } else if (EPI == 1) {
          out1[(size_t)rr*ld1 + col] = f2bf(fmaxf(v, 0.f));
        } else {
          size_t xi = (size_t)rr*256 + col;
          x_io[xi] += bf2f(gt[xi]) * v;
        }
      }
    }
  }
}

// =================================================================================
extern "C" void kernel_launch(void* const* d_in, const int* in_sizes, int n_in,
                              void* d_out, int out_size, void* d_ws, size_t ws_size,
                              hipStream_t stream)
{
  const float* x_in = (const float*)d_in[0];
  const float* pre  = (const float*)d_in[1];
  const float* cc   = (const float*)d_in[2];
  const int*   mask = (const int*)d_in[3];
  const float* wq = (const float*)d_in[4];   const float* bq = (const float*)d_in[5];
  const float* wk = (const float*)d_in[6];   const float* bk = (const float*)d_in[7];
  const float* wv = (const float*)d_in[8];   const float* bvz = (const float*)d_in[9];
  const float* wo = (const float*)d_in[10];  const float* bo = (const float*)d_in[11];
  const float* sa_w1 = (const float*)d_in[12]; const float* sa_b1 = (const float*)d_in[13];
  const float* sa_g1 = (const float*)d_in[14]; const float* sa_sb1 = (const float*)d_in[15];
  const float* sa_w2 = (const float*)d_in[16]; const float* sa_b2 = (const float*)d_in[17];
  const float* sa_g2 = (const float*)d_in[18]; const float* sa_sb2 = (const float*)d_in[19];
  const float* jrp_w = (const float*)d_in[20]; const float* jrp_b = (const float*)d_in[21];
  const float* dwp = (const float*)d_in[22]; const float* swp = (const float*)d_in[23];
  const float* cwp = (const float*)d_in[24]; const float* dsp = (const float*)d_in[25];
  const float* A_hat = (const float*)d_in[26];
  const float* g1w = (const float*)d_in[27]; const float* g1b = (const float*)d_in[28];
  const float* g2w = (const float*)d_in[29]; const float* g2b = (const float*)d_in[30];
  const float* n1g = (const float*)d_in[31]; const float* n1b = (const float*)d_in[32];
  const float* n2g = (const float*)d_in[33]; const float* n2b = (const float*)d_in[34];
  const float* ada1w = (const float*)d_in[35]; const float* ada1b = (const float*)d_in[36];
  const float* ada2w = (const float*)d_in[37]; const float* ada2b = (const float*)d_in[38];

  char* ws = (char*)d_ws;
  size_t off = 0;
  auto alloc = [&](size_t bytes)->char* {
    char* p = ws + off; off = (off + bytes + 255) & ~(size_t)255; return p;
  };

  // -------- fixed region: transposed weights (bf16) + Lm --------
  TJobs jobs;
  int ji = 0;
  auto addjob = [&](const float* src, unsigned short* dst, int Kd, int Nd) {
    jobs.j[ji].src = src; jobs.j[ji].dst = dst; jobs.j[ji].K = Kd; jobs.j[ji].N = Nd;
    ji++;
  };
  unsigned short *t_ada1[2], *t_qsa[2], *t_kv[2], *t_wo[2],
                 *t_sa2[2], *t_jrp[2], *t_g1[2], *t_g2[2], *t_ada2[2];
  for (int L = 0; L < 2; L++) {
    t_ada1[L] = (unsigned short*)alloc((size_t)768*256*2);
    addjob(ada1w + (size_t)L*256*768, t_ada1[L], 256, 768);
    t_qsa[L] = (unsigned short*)alloc((size_t)384*256*2);      // [wq^T ; sa_w1^T]
    addjob(wq + (size_t)L*65536, t_qsa[L], 256, 256);
    addjob(sa_w1 + (size_t)L*256*128, t_qsa[L] + 256*256, 256, 128);
    t_kv[L] = (unsigned short*)alloc((size_t)512*256*2);       // [wk^T ; wv^T]
    addjob(wk + (size_t)L*65536, t_kv[L], 256, 256);
    addjob(wv + (size_t)L*65536, t_kv[L] + 256*256, 256, 256);
    t_wo[L] = (unsigned short*)alloc((size_t)256*256*2);
    addjob(wo + (size_t)L*65536, t_wo[L], 256, 256);
    t_sa2[L] = (unsigned short*)alloc((size_t)64*128*2);
    addjob(sa_w2 + (size_t)L*128*64, t_sa2[L], 128, 64);
    t_jrp[L] = (unsigned short*)alloc((size_t)17*64*2);
    addjob(jrp_w + (size_t)L*64*17, t_jrp[L], 64, 17);
    t_g1[L] = (unsigned short*)alloc((size_t)512*256*2);
    addjob(g1w + (size_t)L*256*512, t_g1[L], 256, 512);
    t_g2[L] = (unsigned short*)alloc((size_t)256*512*2);
    addjob(g2w + (size_t)L*512*256, t_g2[L], 512, 256);
    t_ada2[L] = (unsigned short*)alloc((size_t)768*256*2);
    addjob(ada2w + (size_t)L*256*768, t_ada2[L], 256, 768);
  }
  float* lmbuf = (float*)alloc(2*289*4);
  size_t fixed_bytes = off;

  // -------- pick chunk size so scratch fits ws_size --------
  // per-row scratch: pre_bf 512 + silc 512 + xinb 512 + qbuf 512 + gtbuf 512
  //                + kvb 1024 + skel 68  = 3652 B
  int chunkB = BATCH;
  for (; chunkB > 256; chunkB >>= 1) {
    size_t R = (size_t)chunkB * NJ;
    if (fixed_bytes + R*3652 + 8*256 <= ws_size) break;
  }
  const size_t R = (size_t)chunkB * NJ;          // rows per chunk
  const int nchunks = BATCH / chunkB;

  unsigned short* pre_bf  = (unsigned short*)alloc(R*256*2);
  unsigned short* silc_bf = (unsigned short*)alloc(R*256*2);
  unsigned short* xinb    = (unsigned short*)alloc(R*256*2);   // also hosts jf1/jf2
  unsigned short* qbuf    = (unsigned short*)alloc(R*256*2);   // Q, then att (in place)
  unsigned short* gtbuf   = (unsigned short*)alloc(R*256*2);   // gate columns
  unsigned short* kvb     = (unsigned short*)alloc(R*512*2);   // sh|sc, then K|V, then g1-out
  float*          skelb   = (float*)alloc(R*NJ*4);

  unsigned short* jf1 = xinb;                 // rows x 128 (xinb dead when used)
  unsigned short* jf2 = xinb + R*128;         // rows x 64

  float* xout = (float*)d_out;
  hipMemcpyAsync(xout, x_in, (size_t)BATCH*NJ*256*4, hipMemcpyDeviceToDevice, stream);
  transpose_kernel<<<dim3(768, 22), 256, 0, stream>>>(jobs);
  lm_kernel<<<2, 64, 0, stream>>>(A_hat, lmbuf);

  const int gX = (int)(R/128);    // row blocks (M/128)
  const int g4 = (int)(R/4);      // LN-style grids

  for (int ch = 0; ch < nchunks; ch++) {
    const size_t r0 = (size_t)ch * R;           // global row offset
    const float* pre_c = pre + r0*256;
    const float* cc_c  = cc + r0*256;
    const int* mask_c  = mask + (size_t)ch*chunkB*289;
    float* x_c = xout + r0*256;

    prep_kernel<<<g4, 256, 0, stream>>>(pre_c, cc_c, pre_bf, silc_bf);

    for (int L = 0; L < 2; L++) {
      // ---- sublayer 0: adaLN + skeleton-biased attention ----
      // ada1 fused N=768: cols 0-511 -> kvb (sh|sc, ld 512), cols 512-767 -> gtbuf
      gemm_lds_kernel<0><<<dim3(6,gX),256,0,stream>>>(silc_bf, t_ada1[L],
          ada1b + L*768, nullptr, kvb, 512, gtbuf, 256, 512, nullptr, nullptr, 256);
      lnmod_kernel<<<g4,256,0,stream>>>(x_c, kvb, n1g + L*256, n1b + L*256, xinb);
      // K|V fused N=512 -> kvb [R][512] (runs before qsa: jf1 aliases xinb)
      gemm_lds_kernel<0><<<dim3(4,gX),256,0,stream>>>(xinb, t_kv[L],
          bk + L*256, bvz + L*256, kvb, 512, nullptr, 0, 256, nullptr, nullptr, 256);
      // Q + sa1 fused N=384: cols 0-255 -> qbuf, cols 256-383 -> jf1
      gemm_lds_kernel<0><<<dim3(3,gX),256,0,stream>>>(pre_bf, t_qsa[L],
          bq + L*256, sa_b1 + L*128, qbuf, 256, jf1, 128, 256, nullptr, nullptr, 256);
      lnstd_relu_kernel<128><<<g4,256,0,stream>>>(jf1, sa_g1 + L*128, sa_sb1 + L*128);
      gemm_kernel<4,2,0><<<dim3(gX,1),256,0,stream>>>(jf1, t_sa2[L], sa_b2 + L*64, jf2, nullptr, nullptr, 64, 128);
      lnstd_relu_kernel<64><<<g4,256,0,stream>>>(jf2, sa_g2 + L*64, sa_sb2 + L*64);
      skel_kernel<<<(int)(R*NJ/256),256,0,stream>>>(jf2, t_jrp[L], jrp_b + L*17, dwp+L, swp+L, cwp+L, dsp+L, skelb);
      attn_kernel<<<chunkB,320,0,stream>>>(qbuf, kvb, skelb, mask_c, qbuf);
      gemm_lds_kernel<3><<<dim3(2,gX),256,0,stream>>>(qbuf, t_wo[L],
          bo + L*256, nullptr, nullptr, 0, nullptr, 0, 0, x_c, gtbuf, 256);
      // ---- sublayer 1: adaLN + GraphNet ----
      gemm_lds_kernel<0><<<dim3(6,gX),256,0,stream>>>(silc_bf, t_ada2[L],
          ada2b + L*768, nullptr, kvb, 512, gtbuf, 256, 512, nullptr, nullptr, 256);
      lnmod_kernel<<<g4,256,0,stream>>>(x_c, kvb, n2g + L*256, n2b + L*256, xinb);
      lmapply_kernel<256><<<chunkB,256,0,stream>>>(xinb, lmbuf + L*289);
      gemm_lds_kernel<1><<<dim3(4,gX),256,0,stream>>>(xinb, t_g1[L],
          g1b + L*512, nullptr, kvb, 512, nullptr, 0, 0, nullptr, nullptr, 256);
      lmapply_kernel<512><<<chunkB,256,0,stream>>>(kvb, lmbuf + L*289);
      gemm_lds_kernel<3><<<dim3(2,gX),256,0,stream>>>(kvb, t_g2[L],
          g2b + L*256, nullptr, nullptr, 0, nullptr, 0, 0, x_c, gtbuf, 512);
    }
  }
}

// Round 7
// 1584.973 us; speedup vs baseline: 1.1626x; 1.1626x over previous
//
#include <hip/hip_runtime.h>
#include <stdint.h>

// GraFormer forward, MI355X gfx950.
// x (residual) kept fp32 in d_out, updated in place by GEMM epilogues.
// All GEMM operands bf16 (MFMA 16x16x32), fp32 accumulate.
// R1-R3: LDS-staged GEMM + pipeline + XCD swizzle + fusions.
// R4/R5: attn d-split + block-per-batch-elem LDS staging.
// R6 (failed): 128KB single-shot -> 1 block/CU, occupancy 9%, regressed.
// R7: occupancy-first GEMM: 64x64 tile, 256 thr (4 waves, 32x32/wave,
//     acc[2][2]=16 AGPR), BK=64 double-buffered 32KB LDS, counted vmcnt(4),
//     __launch_bounds__(256,4) -> 4 blocks/CU = 16 waves/CU. Latency of one
//     block's staging hides under 3 other resident blocks' compute.
//     slot^(row&7) swizzle (pre-swizzled global source; same XOR on ds_read).

#define BATCH 4096
#define NJ 17
#define NHEAD 8

typedef __bf16 bf16x8 __attribute__((ext_vector_type(8)));
typedef float f32x4 __attribute__((ext_vector_type(4)));

__device__ __forceinline__ float bf2f(unsigned short u){
  union { unsigned int i; float f; } v; v.i = ((unsigned int)u) << 16; return v.f;
}
__device__ __forceinline__ unsigned short f2bf(float f){
  union { float f; unsigned int i; } v; v.f = f;
  unsigned int i = v.i;
  return (unsigned short)((i + 0x7fffu + ((i >> 16) & 1u)) >> 16);
}
__device__ __forceinline__ float blo(unsigned int v){ union{unsigned int i;float f;}x; x.i=v<<16; return x.f; }
__device__ __forceinline__ float bhi(unsigned int v){ union{unsigned int i;float f;}x; x.i=v&0xffff0000u; return x.f; }

__device__ __forceinline__ void gload_lds16(const void* g, void* l) {
  __builtin_amdgcn_global_load_lds(
      (const __attribute__((address_space(1))) unsigned int*)g,
      (__attribute__((address_space(3))) unsigned int*)l, 16, 0, 0);
}

// ---------------- prep: pre_3d -> bf16, silu(c) -> bf16 (per chunk) ----------------
__global__ __launch_bounds__(256) void prep_kernel(
    const float* __restrict__ pre, const float* __restrict__ c,
    unsigned short* __restrict__ pre_bf, unsigned short* __restrict__ silc_bf)
{
  size_t i = (size_t)(blockIdx.x*256 + threadIdx.x)*4;
  float4 p = *(const float4*)(pre + i);
  float4 cv = *(const float4*)(c + i);
  float s0 = cv.x/(1.f+__expf(-cv.x));
  float s1 = cv.y/(1.f+__expf(-cv.y));
  float s2 = cv.z/(1.f+__expf(-cv.z));
  float s3 = cv.w/(1.f+__expf(-cv.w));
  uint2 po, so;
  po.x = (unsigned)f2bf(p.x) | ((unsigned)f2bf(p.y)<<16);
  po.y = (unsigned)f2bf(p.z) | ((unsigned)f2bf(p.w)<<16);
  so.x = (unsigned)f2bf(s0) | ((unsigned)f2bf(s1)<<16);
  so.y = (unsigned)f2bf(s2) | ((unsigned)f2bf(s3)<<16);
  *(uint2*)(pre_bf + i) = po;
  *(uint2*)(silc_bf + i) = so;
}

// ---------------- batched weight transpose+convert: dst[n*K+k] = bf16(src[k*N+n]) ----
struct TJob { const float* src; unsigned short* dst; int K; int N; };
struct TJobs { TJob j[22]; };

__global__ __launch_bounds__(256) void transpose_kernel(TJobs jobs)
{
  TJob jb = jobs.j[blockIdx.y];
  int total = jb.K * jb.N;
  int idx = blockIdx.x*256 + threadIdx.x;
  if (idx >= total) return;
  int n = idx / jb.K;
  int k = idx - n*jb.K;
  jb.dst[idx] = f2bf(jb.src[(size_t)k*jb.N + n]);
}

// ---------------- Lm = dh[:,None]*A*dh[None,:], dh=(colsum+1e-5)^-0.5 -----------
__global__ void lm_kernel(const float* __restrict__ A_hat, float* __restrict__ LmOut)
{
  int L = blockIdx.x;
  const float* a = A_hat + L*289;
  float* Lm = LmOut + L*289;
  __shared__ float dh[17];
  int t = threadIdx.x;
  if (t < 17) {
    float s = 0;
    for (int i = 0; i < 17; i++) s += a[i*17 + t];
    dh[t] = 1.0f/sqrtf(s + 1e-5f);
  }
  __syncthreads();
  for (int i = t; i < 289; i += 64) {
    int qq = i/17, jj = i - qq*17;
    Lm[i] = dh[qq]*a[i]*dh[jj];
  }
}

// ---- custom-LN (unbiased std, eps added to std) + adaLN modulate ----
// shsc: [rows, 512] bf16 (sh = cols 0-255, sc = cols 256-511)
__global__ __launch_bounds__(256) void lnmod_kernel(
    const float* __restrict__ x, const unsigned short* __restrict__ shsc,
    const float* __restrict__ g, const float* __restrict__ b,
    unsigned short* __restrict__ out)
{
  int row = blockIdx.x*4 + (threadIdx.x>>6);
  int lane = threadIdx.x & 63;
  const float4 v = *(const float4*)(x + (size_t)row*256 + lane*4);
  float s = v.x+v.y+v.z+v.w;
#pragma unroll
  for (int o=32;o;o>>=1) s += __shfl_down(s,o,64);
  float mu = __shfl(s,0,64) * (1.f/256.f);
  float d0=v.x-mu,d1=v.y-mu,d2=v.z-mu,d3=v.w-mu;
  float qq = d0*d0+d1*d1+d2*d2+d3*d3;
#pragma unroll
  for (int o=32;o;o>>=1) qq += __shfl_down(qq,o,64);
  qq = __shfl(qq,0,64);
  float rstd = 1.f/(sqrtf(qq*(1.f/255.f)) + 1e-6f);
  int c = lane*4;
  const float4 gv = *(const float4*)(g + c);
  const float4 bv = *(const float4*)(b + c);
  const uint2 shp = *(const uint2*)(shsc + (size_t)row*512 + c);
  const uint2 scp = *(const uint2*)(shsc + (size_t)row*512 + 256 + c);
  float o0 = (gv.x*d0*rstd + bv.x)*(1.f+blo(scp.x)) + blo(shp.x);
  float o1 = (gv.y*d1*rstd + bv.y)*(1.f+bhi(scp.x)) + bhi(shp.x);
  float o2 = (gv.z*d2*rstd + bv.z)*(1.f+blo(scp.y)) + blo(shp.y);
  float o3 = (gv.w*d3*rstd + bv.w)*(1.f+bhi(scp.y)) + bhi(shp.y);
  uint2 ov;
  ov.x = (unsigned)f2bf(o0) | ((unsigned)f2bf(o1)<<16);
  ov.y = (unsigned)f2bf(o2) | ((unsigned)f2bf(o3)<<16);
  *(uint2*)(out + (size_t)row*256 + c) = ov;
}

// ---------------- standard LN (biased var, eps in sqrt) + relu, in place, bf16 ----
template<int C>
__global__ __launch_bounds__(256) void lnstd_relu_kernel(
    unsigned short* __restrict__ io, const float* __restrict__ g, const float* __restrict__ b)
{
  constexpr int EPL = C/64;
  int row = blockIdx.x*4 + (threadIdx.x>>6);
  int lane = threadIdx.x & 63;
  unsigned short* rp = io + (size_t)row*C + lane*EPL;
  float v[EPL];
  if constexpr (EPL == 2) { unsigned int u = *(const unsigned int*)rp; v[0]=blo(u); v[1]=bhi(u); }
  else { v[0] = bf2f(rp[0]); }
  float s = 0;
#pragma unroll
  for (int e=0;e<EPL;e++) s += v[e];
#pragma unroll
  for (int o=32;o;o>>=1) s += __shfl_down(s,o,64);
  float mu = __shfl(s,0,64) * (1.f/C);
  float qq = 0;
#pragma unroll
  for (int e=0;e<EPL;e++){ float d=v[e]-mu; qq += d*d; }
#pragma unroll
  for (int o=32;o;o>>=1) qq += __shfl_down(qq,o,64);
  qq = __shfl(qq,0,64);
  float rstd = rsqrtf(qq*(1.f/C) + 1e-5f);
  unsigned short ov[EPL];
#pragma unroll
  for (int e=0;e<EPL;e++){
    int ccol = lane*EPL + e;
    float o = fmaxf(g[ccol]*(v[e]-mu)*rstd + b[ccol], 0.f);
    ov[e] = f2bf(o);
  }
  if constexpr (EPL==2){ *(unsigned int*)rp = (unsigned)ov[0] | ((unsigned)ov[1]<<16); }
  else rp[0] = ov[0];
}

// ---------------- skel = base_mask + sigmoid(jf2 @ jrp_w + jrp_b)*dyn_scale ------
__global__ __launch_bounds__(256) void skel_kernel(
    const unsigned short* __restrict__ jf2, const unsigned short* __restrict__ jrpt,
    const float* __restrict__ jrp_b,
    const float* __restrict__ dwp, const float* __restrict__ swp,
    const float* __restrict__ cwp, const float* __restrict__ dsp,
    float* __restrict__ skel)
{
  int gid = blockIdx.x*256 + threadIdx.x;
  int row = gid / 17;
  int k = gid - row*17;
  int q = row % 17;
  const uint4* a = (const uint4*)(jf2 + (size_t)row*64);
  const uint4* w = (const uint4*)(jrpt + k*64);
  float acc = jrp_b[k];
#pragma unroll
  for (int c = 0; c < 8; c++) {
    uint4 ua = a[c], uw = w[c];
    acc += blo(ua.x)*blo(uw.x) + bhi(ua.x)*bhi(uw.x)
         + blo(ua.y)*blo(uw.y) + bhi(ua.y)*bhi(uw.y)
         + blo(ua.z)*blo(uw.z) + bhi(ua.z)*bhi(uw.z)
         + blo(ua.w)*blo(uw.w) + bhi(ua.w)*bhi(uw.w);
  }
  float sig = 1.f/(1.f + __expf(-acc));
  float base = 1.f;
  const int dqa[16] = {0,1,2,0,4,5,0,7,8,9,8,11,12,8,14,15};
  const int dka[16] = {1,2,3,4,5,6,7,8,9,10,11,12,13,14,15,16};
#pragma unroll
  for (int t = 0; t < 16; t++) if (q==dqa[t] && k==dka[t]) base += dwp[0];
  const int s0a[6] = {1,2,3,11,12,13};
  const int s1a[6] = {4,5,6,14,15,16};
#pragma unroll
  for (int t = 0; t < 6; t++) if ((q==s0a[t]&&k==s1a[t])||(q==s1a[t]&&k==s0a[t])) base += swp[0];
  if (q==k) base += cwp[0];
  skel[gid] = base + sig*dsp[0];
}

// ---------------- attention: block per batch elem, KV/skel/mask in LDS ----------
// KV: [rows][512] bf16, K = cols 0-255, V = cols 256-511.
// 320 threads (5 waves); threads 0..271 active: pair (2t,2t+1) shares one
// (h,q), 16 dims each; partial QK dots combined via __shfl_xor(.,1).
__device__ __forceinline__ void load16f(const unsigned short* p, float* f){
  const uint4* p4 = (const uint4*)p;
#pragma unroll
  for (int c=0;c<2;c++){
    uint4 u=p4[c];
    f[c*8+0]=blo(u.x); f[c*8+1]=bhi(u.x); f[c*8+2]=blo(u.y); f[c*8+3]=bhi(u.y);
    f[c*8+4]=blo(u.z); f[c*8+5]=bhi(u.z); f[c*8+6]=blo(u.w); f[c*8+7]=bhi(u.w);
  }
}

__global__ __launch_bounds__(320) void attn_kernel(
    const unsigned short* Q, const unsigned short* __restrict__ KV,
    const float* __restrict__ skel,
    const int* __restrict__ mask, unsigned short* att)
{
  __shared__ unsigned short kvs[17*512];   // 17408 B
  __shared__ float sks[289];
  __shared__ int   mks[289];
  const int b = blockIdx.x;
  const int tid = threadIdx.x;

  const uint4* src = (const uint4*)(KV + (size_t)b*17*512);
  for (int i = tid; i < 1088; i += 320) ((uint4*)kvs)[i] = src[i];
  const float* skb = skel + (size_t)b*289;
  const int* mkb = mask + (size_t)b*289;
  for (int i = tid; i < 289; i += 320) { sks[i] = skb[i]; mks[i] = mkb[i]; }
  __syncthreads();
  if (tid >= 272) return;

  const int t2 = tid >> 1;            // (h,q) work item, 0..135
  const int dh = tid & 1;             // d-half
  const int h = t2 / 17;
  const int q = t2 - h*17;
  const int col = h*32 + dh*16;       // column offset within a KV row (shorts)
  size_t rq = ((size_t)(b*17+q))*256 + col;
  float qv[16];
  load16f(Q + rq, qv);

  float p[17];
  float mx = -3e38f;
#pragma unroll
  for (int k = 0; k < 17; k++) {
    const uint4* kp = (const uint4*)(kvs + k*512 + col);
    float s = 0;
#pragma unroll
    for (int c = 0; c < 2; c++) {
      uint4 u = kp[c];
      s += qv[c*8+0]*blo(u.x) + qv[c*8+1]*bhi(u.x)
         + qv[c*8+2]*blo(u.y) + qv[c*8+3]*bhi(u.y)
         + qv[c*8+4]*blo(u.z) + qv[c*8+5]*bhi(u.z)
         + qv[c*8+6]*blo(u.w) + qv[c*8+7]*bhi(u.w);
    }
    s += __shfl_xor(s, 1, 64);        // combine the two d-halves
    s *= 0.17677669529663687f;        // 1/sqrt(32)
    float gvl = (mks[q*17+k]==0) ? -1e9f : s*sks[q*17+k];
    p[k] = gvl;
    mx = fmaxf(mx, gvl);
  }
  float sum = 0;
#pragma unroll
  for (int k = 0; k < 17; k++){ p[k] = __expf(p[k]-mx); sum += p[k]; }
  float inv = 1.f/sum;
  float acc[16];
#pragma unroll
  for (int d=0; d<16; d++) acc[d]=0;
#pragma unroll
  for (int k = 0; k < 17; k++) {
    float pk = p[k]*inv;
    const uint4* vp = (const uint4*)(kvs + k*512 + 256 + col);
#pragma unroll
    for (int c=0;c<2;c++){
      uint4 u=vp[c];
      acc[c*8+0] += pk*blo(u.x); acc[c*8+1] += pk*bhi(u.x);
      acc[c*8+2] += pk*blo(u.y); acc[c*8+3] += pk*bhi(u.y);
      acc[c*8+4] += pk*blo(u.z); acc[c*8+5] += pk*bhi(u.z);
      acc[c*8+6] += pk*blo(u.w); acc[c*8+7] += pk*bhi(u.w);
    }
  }
  uint4 o[2];
#pragma unroll
  for (int c=0;c<2;c++){
    o[c].x = (unsigned)f2bf(acc[c*8+0]) | ((unsigned)f2bf(acc[c*8+1])<<16);
    o[c].y = (unsigned)f2bf(acc[c*8+2]) | ((unsigned)f2bf(acc[c*8+3])<<16);
    o[c].z = (unsigned)f2bf(acc[c*8+4]) | ((unsigned)f2bf(acc[c*8+5])<<16);
    o[c].w = (unsigned)f2bf(acc[c*8+6]) | ((unsigned)f2bf(acc[c*8+7])<<16);
  }
  uint4* op = (uint4*)(att + rq);
  op[0] = o[0]; op[1] = o[1];
}

// ---------------- Lm @ y per batch-elem, in place (17xD), D = 256 or 512 ---------
template<int D>
__global__ __launch_bounds__(256) void lmapply_kernel(
    unsigned short* __restrict__ io, const float* __restrict__ Lm)
{
  __shared__ unsigned short ys[17*D];
  __shared__ float lms[289];
  int b = blockIdx.x;
  int tid = threadIdx.x;
  unsigned short* base = io + (size_t)b*17*D;
  constexpr int CH = 17*D/8;
  for (int i = tid; i < CH; i += 256) ((uint4*)ys)[i] = ((const uint4*)base)[i];
  for (int i = tid; i < 289; i += 256) lms[i] = Lm[i];
  __syncthreads();
#pragma unroll
  for (int c0 = 0; c0 < D; c0 += 256) {
    int c = c0 + tid;
    float yv[17];
#pragma unroll
    for (int j = 0; j < 17; j++) yv[j] = bf2f(ys[j*D + c]);
#pragma unroll
    for (int qi = 0; qi < 17; qi++) {
      float a = 0;
#pragma unroll
      for (int j = 0; j < 17; j++) a += lms[qi*17+j]*yv[j];
      base[qi*D + c] = f2bf(a);
    }
  }
}

// ---------------- small GEMM (register-direct, kept for N=64): ------------------
template<int TM, int TN, int EPI>
__global__ __launch_bounds__(256) void gemm_kernel(
    const unsigned short* __restrict__ A, const unsigned short* __restrict__ Bt,
    const float* __restrict__ bias, unsigned short* __restrict__ outbf,
    float* __restrict__ x_io, const unsigned short* __restrict__ gt,
    int N, int K)
{
  int lane = threadIdx.x & 63;
  int wave = threadIdx.x >> 6;
  int lm = lane & 15, quad = lane >> 4;
  int wm0 = blockIdx.x*(2*TM*16) + (wave>>1)*(TM*16);
  int wn0 = blockIdx.y*(2*TN*16) + (wave&1)*(TN*16);
  const unsigned short* pa[TM];
  const unsigned short* pb[TN];
#pragma unroll
  for (int t=0;t<TM;t++) pa[t] = A + (size_t)(wm0 + t*16 + lm)*K + quad*8;
#pragma unroll
  for (int t=0;t<TN;t++) pb[t] = Bt + (size_t)(wn0 + t*16 + lm)*K + quad*8;
  f32x4 acc[TM][TN] = {};
  for (int kc = 0; kc < K; kc += 32) {
    bf16x8 af[TM], bfv[TN];
#pragma unroll
    for (int t=0;t<TM;t++) af[t] = *(const bf16x8*)(pa[t] + kc);
#pragma unroll
    for (int t=0;t<TN;t++) bfv[t] = *(const bf16x8*)(pb[t] + kc);
#pragma unroll
    for (int i=0;i<TM;i++)
#pragma unroll
      for (int j=0;j<TN;j++)
        acc[i][j] = __builtin_amdgcn_mfma_f32_16x16x32_bf16(af[i], bfv[j], acc[i][j], 0, 0, 0);
  }
#pragma unroll
  for (int j=0;j<TN;j++) {
    int col = wn0 + j*16 + lm;
    float bv = bias[col];
#pragma unroll
    for (int i=0;i<TM;i++) {
      int r0 = wm0 + i*16 + quad*4;
#pragma unroll
      for (int e=0;e<4;e++) {
        int rr = r0 + e;
        float v = acc[i][j][e] + bv;
        if (EPI == 0) {
          outbf[(size_t)rr*N + col] = f2bf(v);
        } else if (EPI == 1) {
          outbf[(size_t)rr*N + col] = f2bf(fmaxf(v, 0.f));
        } else {
          size_t xi = (size_t)rr*N + col;
          x_io[xi] += bf2f(gt[(size_t)rr*256 + col]) * v;
        }
      }
    }
  }
}

// ---------------- main GEMM: 64x64 tile, BK=64 dbuf, 4 blocks/CU ---------------
// grid = (N/64, M/64), XCD-bijective remap (A-panel L2 reuse).
// 256 thr = 4 waves, each owns a 32x32 quadrant (acc[2][2] = 16 AGPR).
// LDS: As/Bs [2 buf][64 rows][64 shorts] = 32 KB total -> with ~70 regs and
// __launch_bounds__(256,4): 4 blocks/CU = 16 waves/CU. Counted vmcnt(4):
// stage next BK=64 tile (4 gload_lds/wave) while computing current.
// Swizzle: physical 16B slot p of row r holds global slot p^(r&7) (applied on
// global source; same XOR on ds_read) -> b128 reads spread over all 8 slot
// groups (optimal 8-cycle wave64 b128).
// EPI: 0 = store bf16 (optional split at splitN -> out2), 1 = relu store,
//      3 = x_io += bf2f(gt)*val (N=256 fixed).
template<int EPI>
__global__ __launch_bounds__(256, 4) void gemm_lds_kernel(
    const unsigned short* __restrict__ A, const unsigned short* __restrict__ Bt,
    const float* __restrict__ bias, const float* __restrict__ bias2,
    unsigned short* __restrict__ out1, int ld1,
    unsigned short* __restrict__ out2, int ld2, int splitN,
    float* __restrict__ x_io, const unsigned short* __restrict__ gt,
    int K)
{
  __shared__ unsigned short As[2][64*64];   // 8 KB per buf
  __shared__ unsigned short Bs[2][64*64];
  const int tid = threadIdx.x;
  const int lane = tid & 63;
  const int wave = tid >> 6;
  const int lm = lane & 15, quad = lane >> 4;

  // bijective XCD remap: flat -> wg such that each XCD owns a contiguous range
  const int gx = gridDim.x;
  const int nwg = gx * (int)gridDim.y;
  int flat = (int)blockIdx.y * gx + (int)blockIdx.x;
  int xcd = flat & 7, idx = flat >> 3;
  int qd = nwg >> 3, rm = nwg & 7;
  int wg = (xcd < rm ? xcd*(qd+1) : rm*(qd+1) + (xcd-rm)*qd) + idx;
  int by = wg / gx, bx = wg - by*gx;
  const int m0 = by * 64;
  const int n0 = bx * 64;
  const int wm = (wave >> 1) * 32;
  const int wn = (wave & 1) * 32;

  // staging: 64 rows x 8 slots(16B) = 512 slots per matrix; 2 per thread
  auto stage = [&](int buf, int kc) {
#pragma unroll
    for (int j = 0; j < 2; j++) {
      int sidx = tid + 256*j;         // 0..511
      int row = sidx >> 3;            // 0..63
      int gs = (sidx & 7) ^ (row & 7);
      gload_lds16(A  + (size_t)(m0 + row)*K + kc + gs*8, As[buf] + sidx*8);
      gload_lds16(Bt + (size_t)(n0 + row)*K + kc + gs*8, Bs[buf] + sidx*8);
    }
  };

  const int nt = K >> 6;              // K/64 (4 or 8)
  stage(0, 0);

  f32x4 acc[2][2] = {};
  int cur = 0;
  for (int t = 0; t < nt; t++) {
    if (t + 1 < nt) {
      stage(cur ^ 1, (t+1)*64);
      asm volatile("s_waitcnt vmcnt(4)" ::: "memory");   // current tile landed
    } else {
      asm volatile("s_waitcnt vmcnt(0)" ::: "memory");
    }
    __builtin_amdgcn_s_barrier();

    const unsigned short* as_ = As[cur];
    const unsigned short* bs_ = Bs[cur];
#pragma unroll
    for (int kh = 0; kh < 2; kh++) {
      bf16x8 af[2], bfv[2];
#pragma unroll
      for (int tt = 0; tt < 2; tt++) {
        int ra = wm + tt*16 + lm;
        af[tt]  = *(const bf16x8*)(as_ + ra*64 + ((((kh<<2)|quad) ^ (ra & 7)) << 3));
        int rb = wn + tt*16 + lm;
        bfv[tt] = *(const bf16x8*)(bs_ + rb*64 + ((((kh<<2)|quad) ^ (rb & 7)) << 3));
      }
#pragma unroll
      for (int i = 0; i < 2; i++)
#pragma unroll
        for (int j = 0; j < 2; j++)
          acc[i][j] = __builtin_amdgcn_mfma_f32_16x16x32_bf16(af[i], bfv[j], acc[i][j], 0, 0, 0);
    }
    __builtin_amdgcn_s_barrier();     // all waves done reading cur before overwrite
    cur ^= 1;
  }

#pragma unroll
  for (int j = 0; j < 2; j++) {
    int col = n0 + wn + j*16 + lm;
    float bv = (bias2 && col >= splitN) ? bias2[col - splitN] : bias[col];
#pragma unroll
    for (int i = 0; i < 2; i++) {
      int r0 = m0 + wm + i*16 + quad*4;
#pragma unroll
      for (int e = 0; e < 4; e++) {
        int rr = r0 + e;
        float v = acc[i][j][e] + bv;
        if (EPI == 0) {
          if (out2 && col >= splitN) out2[(size_t)rr*ld2 + (col - splitN)] = f2bf(v);
          else                       out1[(size_t)rr*ld1 + col] = f2bf(v);
        } else if (EPI == 1) {
          out1[(size_t)rr*ld1 + col] = f2bf(fmaxf(v, 0.f));
        } else {
          size_t xi = (size_t)rr*256 + col;
          x_io[xi] += bf2f(gt[xi]) * v;
        }
      }
    }
  }
}

// =================================================================================
extern "C" void kernel_launch(void* const* d_in, const int* in_sizes, int n_in,
                              void* d_out, int out_size, void* d_ws, size_t ws_size,
                              hipStream_t stream)
{
  const float* x_in = (const float*)d_in[0];
  const float* pre  = (const float*)d_in[1];
  const float* cc   = (const float*)d_in[2];
  const int*   mask = (const int*)d_in[3];
  const float* wq = (const float*)d_in[4];   const float* bq = (const float*)d_in[5];
  const float* wk = (const float*)d_in[6];   const float* bk = (const float*)d_in[7];
  const float* wv = (const float*)d_in[8];   const float* bvz = (const float*)d_in[9];
  const float* wo = (const float*)d_in[10];  const float* bo = (const float*)d_in[11];
  const float* sa_w1 = (const float*)d_in[12]; const float* sa_b1 = (const float*)d_in[13];
  const float* sa_g1 = (const float*)d_in[14]; const float* sa_sb1 = (const float*)d_in[15];
  const float* sa_w2 = (const float*)d_in[16]; const float* sa_b2 = (const float*)d_in[17];
  const float* sa_g2 = (const float*)d_in[18]; const float* sa_sb2 = (const float*)d_in[19];
  const float* jrp_w = (const float*)d_in[20]; const float* jrp_b = (const float*)d_in[21];
  const float* dwp = (const float*)d_in[22]; const float* swp = (const float*)d_in[23];
  const float* cwp = (const float*)d_in[24]; const float* dsp = (const float*)d_in[25];
  const float* A_hat = (const float*)d_in[26];
  const float* g1w = (const float*)d_in[27]; const float* g1b = (const float*)d_in[28];
  const float* g2w = (const float*)d_in[29]; const float* g2b = (const float*)d_in[30];
  const float* n1g = (const float*)d_in[31]; const float* n1b = (const float*)d_in[32];
  const float* n2g = (const float*)d_in[33]; const float* n2b = (const float*)d_in[34];
  const float* ada1w = (const float*)d_in[35]; const float* ada1b = (const float*)d_in[36];
  const float* ada2w = (const float*)d_in[37]; const float* ada2b = (const float*)d_in[38];

  char* ws = (char*)d_ws;
  size_t off = 0;
  auto alloc = [&](size_t bytes)->char* {
    char* p = ws + off; off = (off + bytes + 255) & ~(size_t)255; return p;
  };

  // -------- fixed region: transposed weights (bf16) + Lm --------
  TJobs jobs;
  int ji = 0;
  auto addjob = [&](const float* src, unsigned short* dst, int Kd, int Nd) {
    jobs.j[ji].src = src; jobs.j[ji].dst = dst; jobs.j[ji].K = Kd; jobs.j[ji].N = Nd;
    ji++;
  };
  unsigned short *t_ada1[2], *t_qsa[2], *t_kv[2], *t_wo[2],
                 *t_sa2[2], *t_jrp[2], *t_g1[2], *t_g2[2], *t_ada2[2];
  for (int L = 0; L < 2; L++) {
    t_ada1[L] = (unsigned short*)alloc((size_t)768*256*2);
    addjob(ada1w + (size_t)L*256*768, t_ada1[L], 256, 768);
    t_qsa[L] = (unsigned short*)alloc((size_t)384*256*2);      // [wq^T ; sa_w1^T]
    addjob(wq + (size_t)L*65536, t_qsa[L], 256, 256);
    addjob(sa_w1 + (size_t)L*256*128, t_qsa[L] + 256*256, 256, 128);
    t_kv[L] = (unsigned short*)alloc((size_t)512*256*2);       // [wk^T ; wv^T]
    addjob(wk + (size_t)L*65536, t_kv[L], 256, 256);
    addjob(wv + (size_t)L*65536, t_kv[L] + 256*256, 256, 256);
    t_wo[L] = (unsigned short*)alloc((size_t)256*256*2);
    addjob(wo + (size_t)L*65536, t_wo[L], 256, 256);
    t_sa2[L] = (unsigned short*)alloc((size_t)64*128*2);
    addjob(sa_w2 + (size_t)L*128*64, t_sa2[L], 128, 64);
    t_jrp[L] = (unsigned short*)alloc((size_t)17*64*2);
    addjob(jrp_w + (size_t)L*64*17, t_jrp[L], 64, 17);
    t_g1[L] = (unsigned short*)alloc((size_t)512*256*2);
    addjob(g1w + (size_t)L*256*512, t_g1[L], 256, 512);
    t_g2[L] = (unsigned short*)alloc((size_t)256*512*2);
    addjob(g2w + (size_t)L*512*256, t_g2[L], 512, 256);
    t_ada2[L] = (unsigned short*)alloc((size_t)768*256*2);
    addjob(ada2w + (size_t)L*256*768, t_ada2[L], 256, 768);
  }
  float* lmbuf = (float*)alloc(2*289*4);
  size_t fixed_bytes = off;

  // -------- pick chunk size so scratch fits ws_size --------
  // per-row scratch: pre_bf 512 + silc 512 + xinb 512 + qbuf 512 + gtbuf 512
  //                + kvb 1024 + skel 68  = 3652 B
  int chunkB = BATCH;
  for (; chunkB > 256; chunkB >>= 1) {
    size_t R = (size_t)chunkB * NJ;
    if (fixed_bytes + R*3652 + 8*256 <= ws_size) break;
  }
  const size_t R = (size_t)chunkB * NJ;          // rows per chunk
  const int nchunks = BATCH / chunkB;

  unsigned short* pre_bf  = (unsigned short*)alloc(R*256*2);
  unsigned short* silc_bf = (unsigned short*)alloc(R*256*2);
  unsigned short* xinb    = (unsigned short*)alloc(R*256*2);   // also hosts jf1/jf2
  unsigned short* qbuf    = (unsigned short*)alloc(R*256*2);   // Q, then att (in place)
  unsigned short* gtbuf   = (unsigned short*)alloc(R*256*2);   // gate columns
  unsigned short* kvb     = (unsigned short*)alloc(R*512*2);   // sh|sc, then K|V, then g1-out
  float*          skelb   = (float*)alloc(R*NJ*4);

  unsigned short* jf1 = xinb;                 // rows x 128 (xinb dead when used)
  unsigned short* jf2 = xinb + R*128;         // rows x 64

  float* xout = (float*)d_out;
  hipMemcpyAsync(xout, x_in, (size_t)BATCH*NJ*256*4, hipMemcpyDeviceToDevice, stream);
  transpose_kernel<<<dim3(768, 22), 256, 0, stream>>>(jobs);
  lm_kernel<<<2, 64, 0, stream>>>(A_hat, lmbuf);

  const int gX = (int)(R/128);    // 128-row blocks (small gemm)
  const int g64 = (int)(R/64);    // 64-row blocks (main gemm)
  const int g4 = (int)(R/4);      // LN-style grids

  for (int ch = 0; ch < nchunks; ch++) {
    const size_t r0 = (size_t)ch * R;           // global row offset
    const float* pre_c = pre + r0*256;
    const float* cc_c  = cc + r0*256;
    const int* mask_c  = mask + (size_t)ch*chunkB*289;
    float* x_c = xout + r0*256;

    prep_kernel<<<g4, 256, 0, stream>>>(pre_c, cc_c, pre_bf, silc_bf);

    for (int L = 0; L < 2; L++) {
      // ---- sublayer 0: adaLN + skeleton-biased attention ----
      // ada1 fused N=768: cols 0-511 -> kvb (sh|sc, ld 512), cols 512-767 -> gtbuf
      gemm_lds_kernel<0><<<dim3(12,g64),256,0,stream>>>(silc_bf, t_ada1[L],
          ada1b + L*768, nullptr, kvb, 512, gtbuf, 256, 512, nullptr, nullptr, 256);
      lnmod_kernel<<<g4,256,0,stream>>>(x_c, kvb, n1g + L*256, n1b + L*256, xinb);
      // K|V fused N=512 -> kvb [R][512] (runs before qsa: jf1 aliases xinb)
      gemm_lds_kernel<0><<<dim3(8,g64),256,0,stream>>>(xinb, t_kv[L],
          bk + L*256, bvz + L*256, kvb, 512, nullptr, 0, 256, nullptr, nullptr, 256);
      // Q + sa1 fused N=384: cols 0-255 -> qbuf, cols 256-383 -> jf1
      gemm_lds_kernel<0><<<dim3(6,g64),256,0,stream>>>(pre_bf, t_qsa[L],
          bq + L*256, sa_b1 + L*128, qbuf, 256, jf1, 128, 256, nullptr, nullptr, 256);
      lnstd_relu_kernel<128><<<g4,256,0,stream>>>(jf1, sa_g1 + L*128, sa_sb1 + L*128);
      gemm_kernel<4,2,0><<<dim3(gX,1),256,0,stream>>>(jf1, t_sa2[L], sa_b2 + L*64, jf2, nullptr, nullptr, 64, 128);
      lnstd_relu_kernel<64><<<g4,256,0,stream>>>(jf2, sa_g2 + L*64, sa_sb2 + L*64);
      skel_kernel<<<(int)(R*NJ/256),256,0,stream>>>(jf2, t_jrp[L], jrp_b + L*17, dwp+L, swp+L, cwp+L, dsp+L, skelb);
      attn_kernel<<<chunkB,320,0,stream>>>(qbuf, kvb, skelb, mask_c, qbuf);
      gemm_lds_kernel<3><<<dim3(4,g64),256,0,stream>>>(qbuf, t_wo[L],
          bo + L*256, nullptr, nullptr, 0, nullptr, 0, 0, x_c, gtbuf, 256);
      // ---- sublayer 1: adaLN + GraphNet ----
      gemm_lds_kernel<0><<<dim3(12,g64),256,0,stream>>>(silc_bf, t_ada2[L],
          ada2b + L*768, nullptr, kvb, 512, gtbuf, 256, 512, nullptr, nullptr, 256);
      lnmod_kernel<<<g4,256,0,stream>>>(x_c, kvb, n2g + L*256, n2b + L*256, xinb);
      lmapply_kernel<256><<<chunkB,256,0,stream>>>(xinb, lmbuf + L*289);
      gemm_lds_kernel<1><<<dim3(8,g64),256,0,stream>>>(xinb, t_g1[L],
          g1b + L*512, nullptr, kvb, 512, nullptr, 0, 0, nullptr, nullptr, 256);
      lmapply_kernel<512><<<chunkB,256,0,stream>>>(kvb, lmbuf + L*289);
      gemm_lds_kernel<3><<<dim3(4,g64),256,0,stream>>>(kvb, t_g2[L],
          g2b + L*256, nullptr, nullptr, 0, nullptr, 0, 0, x_c, gtbuf, 512);
    }
  }
}

// Round 8
// 1533.359 us; speedup vs baseline: 1.2018x; 1.0337x over previous
//
#include <hip/hip_runtime.h>
#include <stdint.h>

// GraFormer forward, MI355X gfx950.
// x (residual) kept fp32 in d_out, updated in place by GEMM epilogues.
// All GEMM operands bf16 (MFMA 16x16x32), fp32 accumulate.
// R1-R3: LDS-staged GEMM + pipeline + XCD swizzle + fusions.
// R4/R5: attn d-split + block-per-batch-elem LDS staging.
// R6 (failed): 128KB single-shot -> 1 block/CU, occupancy 9%.
// R7: 64x64 tile / 32x32 per wave, 4 blocks/CU -> MfmaUtil 12.6%, 86us ada.
// R8: fatten wave tile 32x32 -> 64x32 (acc[4][2]): block 128x64, 4 waves,
//     BK=64 dbuf 48KB LDS -> 3 blocks/CU (12 waves). LDS reads per MFMA drop
//     1.0 -> 1.33 MFMA/b128 (LDS pipe was 3:1 over MFMA in R7's audit).
//     Same 128B-row slot^(row&7) swizzle (0 conflicts), counted vmcnt(6).

#define BATCH 4096
#define NJ 17
#define NHEAD 8

typedef __bf16 bf16x8 __attribute__((ext_vector_type(8)));
typedef float f32x4 __attribute__((ext_vector_type(4)));

__device__ __forceinline__ float bf2f(unsigned short u){
  union { unsigned int i; float f; } v; v.i = ((unsigned int)u) << 16; return v.f;
}
__device__ __forceinline__ unsigned short f2bf(float f){
  union { float f; unsigned int i; } v; v.f = f;
  unsigned int i = v.i;
  return (unsigned short)((i + 0x7fffu + ((i >> 16) & 1u)) >> 16);
}
__device__ __forceinline__ float blo(unsigned int v){ union{unsigned int i;float f;}x; x.i=v<<16; return x.f; }
__device__ __forceinline__ float bhi(unsigned int v){ union{unsigned int i;float f;}x; x.i=v&0xffff0000u; return x.f; }

__device__ __forceinline__ void gload_lds16(const void* g, void* l) {
  __builtin_amdgcn_global_load_lds(
      (const __attribute__((address_space(1))) unsigned int*)g,
      (__attribute__((address_space(3))) unsigned int*)l, 16, 0, 0);
}

// ---------------- prep: pre_3d -> bf16, silu(c) -> bf16 (per chunk) ----------------
__global__ __launch_bounds__(256) void prep_kernel(
    const float* __restrict__ pre, const float* __restrict__ c,
    unsigned short* __restrict__ pre_bf, unsigned short* __restrict__ silc_bf)
{
  size_t i = (size_t)(blockIdx.x*256 + threadIdx.x)*4;
  float4 p = *(const float4*)(pre + i);
  float4 cv = *(const float4*)(c + i);
  float s0 = cv.x/(1.f+__expf(-cv.x));
  float s1 = cv.y/(1.f+__expf(-cv.y));
  float s2 = cv.z/(1.f+__expf(-cv.z));
  float s3 = cv.w/(1.f+__expf(-cv.w));
  uint2 po, so;
  po.x = (unsigned)f2bf(p.x) | ((unsigned)f2bf(p.y)<<16);
  po.y = (unsigned)f2bf(p.z) | ((unsigned)f2bf(p.w)<<16);
  so.x = (unsigned)f2bf(s0) | ((unsigned)f2bf(s1)<<16);
  so.y = (unsigned)f2bf(s2) | ((unsigned)f2bf(s3)<<16);
  *(uint2*)(pre_bf + i) = po;
  *(uint2*)(silc_bf + i) = so;
}

// ---------------- batched weight transpose+convert: dst[n*K+k] = bf16(src[k*N+n]) ----
struct TJob { const float* src; unsigned short* dst; int K; int N; };
struct TJobs { TJob j[22]; };

__global__ __launch_bounds__(256) void transpose_kernel(TJobs jobs)
{
  TJob jb = jobs.j[blockIdx.y];
  int total = jb.K * jb.N;
  int idx = blockIdx.x*256 + threadIdx.x;
  if (idx >= total) return;
  int n = idx / jb.K;
  int k = idx - n*jb.K;
  jb.dst[idx] = f2bf(jb.src[(size_t)k*jb.N + n]);
}

// ---------------- Lm = dh[:,None]*A*dh[None,:], dh=(colsum+1e-5)^-0.5 -----------
__global__ void lm_kernel(const float* __restrict__ A_hat, float* __restrict__ LmOut)
{
  int L = blockIdx.x;
  const float* a = A_hat + L*289;
  float* Lm = LmOut + L*289;
  __shared__ float dh[17];
  int t = threadIdx.x;
  if (t < 17) {
    float s = 0;
    for (int i = 0; i < 17; i++) s += a[i*17 + t];
    dh[t] = 1.0f/sqrtf(s + 1e-5f);
  }
  __syncthreads();
  for (int i = t; i < 289; i += 64) {
    int qq = i/17, jj = i - qq*17;
    Lm[i] = dh[qq]*a[i]*dh[jj];
  }
}

// ---- custom-LN (unbiased std, eps added to std) + adaLN modulate ----
// shsc: [rows, 512] bf16 (sh = cols 0-255, sc = cols 256-511)
__global__ __launch_bounds__(256) void lnmod_kernel(
    const float* __restrict__ x, const unsigned short* __restrict__ shsc,
    const float* __restrict__ g, const float* __restrict__ b,
    unsigned short* __restrict__ out)
{
  int row = blockIdx.x*4 + (threadIdx.x>>6);
  int lane = threadIdx.x & 63;
  const float4 v = *(const float4*)(x + (size_t)row*256 + lane*4);
  float s = v.x+v.y+v.z+v.w;
#pragma unroll
  for (int o=32;o;o>>=1) s += __shfl_down(s,o,64);
  float mu = __shfl(s,0,64) * (1.f/256.f);
  float d0=v.x-mu,d1=v.y-mu,d2=v.z-mu,d3=v.w-mu;
  float qq = d0*d0+d1*d1+d2*d2+d3*d3;
#pragma unroll
  for (int o=32;o;o>>=1) qq += __shfl_down(qq,o,64);
  qq = __shfl(qq,0,64);
  float rstd = 1.f/(sqrtf(qq*(1.f/255.f)) + 1e-6f);
  int c = lane*4;
  const float4 gv = *(const float4*)(g + c);
  const float4 bv = *(const float4*)(b + c);
  const uint2 shp = *(const uint2*)(shsc + (size_t)row*512 + c);
  const uint2 scp = *(const uint2*)(shsc + (size_t)row*512 + 256 + c);
  float o0 = (gv.x*d0*rstd + bv.x)*(1.f+blo(scp.x)) + blo(shp.x);
  float o1 = (gv.y*d1*rstd + bv.y)*(1.f+bhi(scp.x)) + bhi(shp.x);
  float o2 = (gv.z*d2*rstd + bv.z)*(1.f+blo(scp.y)) + blo(shp.y);
  float o3 = (gv.w*d3*rstd + bv.w)*(1.f+bhi(scp.y)) + bhi(shp.y);
  uint2 ov;
  ov.x = (unsigned)f2bf(o0) | ((unsigned)f2bf(o1)<<16);
  ov.y = (unsigned)f2bf(o2) | ((unsigned)f2bf(o3)<<16);
  *(uint2*)(out + (size_t)row*256 + c) = ov;
}

// ---------------- standard LN (biased var, eps in sqrt) + relu, in place, bf16 ----
template<int C>
__global__ __launch_bounds__(256) void lnstd_relu_kernel(
    unsigned short* __restrict__ io, const float* __restrict__ g, const float* __restrict__ b)
{
  constexpr int EPL = C/64;
  int row = blockIdx.x*4 + (threadIdx.x>>6);
  int lane = threadIdx.x & 63;
  unsigned short* rp = io + (size_t)row*C + lane*EPL;
  float v[EPL];
  if constexpr (EPL == 2) { unsigned int u = *(const unsigned int*)rp; v[0]=blo(u); v[1]=bhi(u); }
  else { v[0] = bf2f(rp[0]); }
  float s = 0;
#pragma unroll
  for (int e=0;e<EPL;e++) s += v[e];
#pragma unroll
  for (int o=32;o;o>>=1) s += __shfl_down(s,o,64);
  float mu = __shfl(s,0,64) * (1.f/C);
  float qq = 0;
#pragma unroll
  for (int e=0;e<EPL;e++){ float d=v[e]-mu; qq += d*d; }
#pragma unroll
  for (int o=32;o;o>>=1) qq += __shfl_down(qq,o,64);
  qq = __shfl(qq,0,64);
  float rstd = rsqrtf(qq*(1.f/C) + 1e-5f);
  unsigned short ov[EPL];
#pragma unroll
  for (int e=0;e<EPL;e++){
    int ccol = lane*EPL + e;
    float o = fmaxf(g[ccol]*(v[e]-mu)*rstd + b[ccol], 0.f);
    ov[e] = f2bf(o);
  }
  if constexpr (EPL==2){ *(unsigned int*)rp = (unsigned)ov[0] | ((unsigned)ov[1]<<16); }
  else rp[0] = ov[0];
}

// ---------------- skel = base_mask + sigmoid(jf2 @ jrp_w + jrp_b)*dyn_scale ------
__global__ __launch_bounds__(256) void skel_kernel(
    const unsigned short* __restrict__ jf2, const unsigned short* __restrict__ jrpt,
    const float* __restrict__ jrp_b,
    const float* __restrict__ dwp, const float* __restrict__ swp,
    const float* __restrict__ cwp, const float* __restrict__ dsp,
    float* __restrict__ skel)
{
  int gid = blockIdx.x*256 + threadIdx.x;
  int row = gid / 17;
  int k = gid - row*17;
  int q = row % 17;
  const uint4* a = (const uint4*)(jf2 + (size_t)row*64);
  const uint4* w = (const uint4*)(jrpt + k*64);
  float acc = jrp_b[k];
#pragma unroll
  for (int c = 0; c < 8; c++) {
    uint4 ua = a[c], uw = w[c];
    acc += blo(ua.x)*blo(uw.x) + bhi(ua.x)*bhi(uw.x)
         + blo(ua.y)*blo(uw.y) + bhi(ua.y)*bhi(uw.y)
         + blo(ua.z)*blo(uw.z) + bhi(ua.z)*bhi(uw.z)
         + blo(ua.w)*blo(uw.w) + bhi(ua.w)*bhi(uw.w);
  }
  float sig = 1.f/(1.f + __expf(-acc));
  float base = 1.f;
  const int dqa[16] = {0,1,2,0,4,5,0,7,8,9,8,11,12,8,14,15};
  const int dka[16] = {1,2,3,4,5,6,7,8,9,10,11,12,13,14,15,16};
#pragma unroll
  for (int t = 0; t < 16; t++) if (q==dqa[t] && k==dka[t]) base += dwp[0];
  const int s0a[6] = {1,2,3,11,12,13};
  const int s1a[6] = {4,5,6,14,15,16};
#pragma unroll
  for (int t = 0; t < 6; t++) if ((q==s0a[t]&&k==s1a[t])||(q==s1a[t]&&k==s0a[t])) base += swp[0];
  if (q==k) base += cwp[0];
  skel[gid] = base + sig*dsp[0];
}

// ---------------- attention: block per batch elem, KV/skel/mask in LDS ----------
// KV: [rows][512] bf16, K = cols 0-255, V = cols 256-511.
// 320 threads (5 waves); threads 0..271 active: pair (2t,2t+1) shares one
// (h,q), 16 dims each; partial QK dots combined via __shfl_xor(.,1).
__device__ __forceinline__ void load16f(const unsigned short* p, float* f){
  const uint4* p4 = (const uint4*)p;
#pragma unroll
  for (int c=0;c<2;c++){
    uint4 u=p4[c];
    f[c*8+0]=blo(u.x); f[c*8+1]=bhi(u.x); f[c*8+2]=blo(u.y); f[c*8+3]=bhi(u.y);
    f[c*8+4]=blo(u.z); f[c*8+5]=bhi(u.z); f[c*8+6]=blo(u.w); f[c*8+7]=bhi(u.w);
  }
}

__global__ __launch_bounds__(320) void attn_kernel(
    const unsigned short* Q, const unsigned short* __restrict__ KV,
    const float* __restrict__ skel,
    const int* __restrict__ mask, unsigned short* att)
{
  __shared__ unsigned short kvs[17*512];   // 17408 B
  __shared__ float sks[289];
  __shared__ int   mks[289];
  const int b = blockIdx.x;
  const int tid = threadIdx.x;

  const uint4* src = (const uint4*)(KV + (size_t)b*17*512);
  for (int i = tid; i < 1088; i += 320) ((uint4*)kvs)[i] = src[i];
  const float* skb = skel + (size_t)b*289;
  const int* mkb = mask + (size_t)b*289;
  for (int i = tid; i < 289; i += 320) { sks[i] = skb[i]; mks[i] = mkb[i]; }
  __syncthreads();
  if (tid >= 272) return;

  const int t2 = tid >> 1;            // (h,q) work item, 0..135
  const int dh = tid & 1;             // d-half
  const int h = t2 / 17;
  const int q = t2 - h*17;
  const int col = h*32 + dh*16;       // column offset within a KV row (shorts)
  size_t rq = ((size_t)(b*17+q))*256 + col;
  float qv[16];
  load16f(Q + rq, qv);

  float p[17];
  float mx = -3e38f;
#pragma unroll
  for (int k = 0; k < 17; k++) {
    const uint4* kp = (const uint4*)(kvs + k*512 + col);
    float s = 0;
#pragma unroll
    for (int c = 0; c < 2; c++) {
      uint4 u = kp[c];
      s += qv[c*8+0]*blo(u.x) + qv[c*8+1]*bhi(u.x)
         + qv[c*8+2]*blo(u.y) + qv[c*8+3]*bhi(u.y)
         + qv[c*8+4]*blo(u.z) + qv[c*8+5]*bhi(u.z)
         + qv[c*8+6]*blo(u.w) + qv[c*8+7]*bhi(u.w);
    }
    s += __shfl_xor(s, 1, 64);        // combine the two d-halves
    s *= 0.17677669529663687f;        // 1/sqrt(32)
    float gvl = (mks[q*17+k]==0) ? -1e9f : s*sks[q*17+k];
    p[k] = gvl;
    mx = fmaxf(mx, gvl);
  }
  float sum = 0;
#pragma unroll
  for (int k = 0; k < 17; k++){ p[k] = __expf(p[k]-mx); sum += p[k]; }
  float inv = 1.f/sum;
  float acc[16];
#pragma unroll
  for (int d=0; d<16; d++) acc[d]=0;
#pragma unroll
  for (int k = 0; k < 17; k++) {
    float pk = p[k]*inv;
    const uint4* vp = (const uint4*)(kvs + k*512 + 256 + col);
#pragma unroll
    for (int c=0;c<2;c++){
      uint4 u=vp[c];
      acc[c*8+0] += pk*blo(u.x); acc[c*8+1] += pk*bhi(u.x);
      acc[c*8+2] += pk*blo(u.y); acc[c*8+3] += pk*bhi(u.y);
      acc[c*8+4] += pk*blo(u.z); acc[c*8+5] += pk*bhi(u.z);
      acc[c*8+6] += pk*blo(u.w); acc[c*8+7] += pk*bhi(u.w);
    }
  }
  uint4 o[2];
#pragma unroll
  for (int c=0;c<2;c++){
    o[c].x = (unsigned)f2bf(acc[c*8+0]) | ((unsigned)f2bf(acc[c*8+1])<<16);
    o[c].y = (unsigned)f2bf(acc[c*8+2]) | ((unsigned)f2bf(acc[c*8+3])<<16);
    o[c].z = (unsigned)f2bf(acc[c*8+4]) | ((unsigned)f2bf(acc[c*8+5])<<16);
    o[c].w = (unsigned)f2bf(acc[c*8+6]) | ((unsigned)f2bf(acc[c*8+7])<<16);
  }
  uint4* op = (uint4*)(att + rq);
  op[0] = o[0]; op[1] = o[1];
}

// ---------------- Lm @ y per batch-elem, in place (17xD), D = 256 or 512 ---------
template<int D>
__global__ __launch_bounds__(256) void lmapply_kernel(
    unsigned short* __restrict__ io, const float* __restrict__ Lm)
{
  __shared__ unsigned short ys[17*D];
  __shared__ float lms[289];
  int b = blockIdx.x;
  int tid = threadIdx.x;
  unsigned short* base = io + (size_t)b*17*D;
  constexpr int CH = 17*D/8;
  for (int i = tid; i < CH; i += 256) ((uint4*)ys)[i] = ((const uint4*)base)[i];
  for (int i = tid; i < 289; i += 256) lms[i] = Lm[i];
  __syncthreads();
#pragma unroll
  for (int c0 = 0; c0 < D; c0 += 256) {
    int c = c0 + tid;
    float yv[17];
#pragma unroll
    for (int j = 0; j < 17; j++) yv[j] = bf2f(ys[j*D + c]);
#pragma unroll
    for (int qi = 0; qi < 17; qi++) {
      float a = 0;
#pragma unroll
      for (int j = 0; j < 17; j++) a += lms[qi*17+j]*yv[j];
      base[qi*D + c] = f2bf(a);
    }
  }
}

// ---------------- small GEMM (register-direct, kept for N=64): ------------------
template<int TM, int TN, int EPI>
__global__ __launch_bounds__(256) void gemm_kernel(
    const unsigned short* __restrict__ A, const unsigned short* __restrict__ Bt,
    const float* __restrict__ bias, unsigned short* __restrict__ outbf,
    float* __restrict__ x_io, const unsigned short* __restrict__ gt,
    int N, int K)
{
  int lane = threadIdx.x & 63;
  int wave = threadIdx.x >> 6;
  int lm = lane & 15, quad = lane >> 4;
  int wm0 = blockIdx.x*(2*TM*16) + (wave>>1)*(TM*16);
  int wn0 = blockIdx.y*(2*TN*16) + (wave&1)*(TN*16);
  const unsigned short* pa[TM];
  const unsigned short* pb[TN];
#pragma unroll
  for (int t=0;t<TM;t++) pa[t] = A + (size_t)(wm0 + t*16 + lm)*K + quad*8;
#pragma unroll
  for (int t=0;t<TN;t++) pb[t] = Bt + (size_t)(wn0 + t*16 + lm)*K + quad*8;
  f32x4 acc[TM][TN] = {};
  for (int kc = 0; kc < K; kc += 32) {
    bf16x8 af[TM], bfv[TN];
#pragma unroll
    for (int t=0;t<TM;t++) af[t] = *(const bf16x8*)(pa[t] + kc);
#pragma unroll
    for (int t=0;t<TN;t++) bfv[t] = *(const bf16x8*)(pb[t] + kc);
#pragma unroll
    for (int i=0;i<TM;i++)
#pragma unroll
      for (int j=0;j<TN;j++)
        acc[i][j] = __builtin_amdgcn_mfma_f32_16x16x32_bf16(af[i], bfv[j], acc[i][j], 0, 0, 0);
  }
#pragma unroll
  for (int j=0;j<TN;j++) {
    int col = wn0 + j*16 + lm;
    float bv = bias[col];
#pragma unroll
    for (int i=0;i<TM;i++) {
      int r0 = wm0 + i*16 + quad*4;
#pragma unroll
      for (int e=0;e<4;e++) {
        int rr = r0 + e;
        float v = acc[i][j][e] + bv;
        if (EPI == 0) {
          outbf[(size_t)rr*N + col] = f2bf(v);
        } else if (EPI == 1) {
          outbf[(size_t)rr*N + col] = f2bf(fmaxf(v, 0.f));
        } else {
          size_t xi = (size_t)rr*N + col;
          x_io[xi] += bf2f(gt[(size_t)rr*256 + col]) * v;
        }
      }
    }
  }
}

// ---------------- main GEMM: 128x64 block, 64x32 wave tile, BK=64 dbuf ----------
// grid = (N/64, M/128), XCD-bijective remap (A-panel L2 reuse).
// 256 thr = 4 waves (2x2 of 64x32 tiles), acc[4][2] = 32 AGPR.
// LDS: As[2][128][64] 32KB + Bs[2][64][64] 16KB = 48KB -> 3 blocks/CU
// (12 waves/CU). Per BK tile per wave: 12 b128 reads -> 16 MFMA (1.33
// MFMA/read vs 1.0 in R7; LDS pipe was the 3:1 bottleneck).
// Counted vmcnt(6): stage next tile (6 gload_lds/thread) while computing.
// Swizzle: physical 16B slot p of row r (128B rows, 8 slots) holds global
// slot p^(r&7); applied on global source, same XOR on ds_read -> 0 conflicts.
// EPI: 0 = store bf16 (optional split at splitN -> out2), 1 = relu store,
//      3 = x_io += bf2f(gt)*val (N=256 fixed).
template<int EPI>
__global__ __launch_bounds__(256, 3) void gemm_lds_kernel(
    const unsigned short* __restrict__ A, const unsigned short* __restrict__ Bt,
    const float* __restrict__ bias, const float* __restrict__ bias2,
    unsigned short* __restrict__ out1, int ld1,
    unsigned short* __restrict__ out2, int ld2, int splitN,
    float* __restrict__ x_io, const unsigned short* __restrict__ gt,
    int K)
{
  __shared__ unsigned short As[2][128*64];   // 16 KB per buf
  __shared__ unsigned short Bs[2][64*64];    //  8 KB per buf
  const int tid = threadIdx.x;
  const int lane = tid & 63;
  const int wave = tid >> 6;
  const int lm = lane & 15, quad = lane >> 4;

  // bijective XCD remap: flat -> wg such that each XCD owns a contiguous range
  const int gx = gridDim.x;
  const int nwg = gx * (int)gridDim.y;
  int flat = (int)blockIdx.y * gx + (int)blockIdx.x;
  int xcd = flat & 7, idx = flat >> 3;
  int qd = nwg >> 3, rm = nwg & 7;
  int wg = (xcd < rm ? xcd*(qd+1) : rm*(qd+1) + (xcd-rm)*qd) + idx;
  int by = wg / gx, bx = wg - by*gx;
  const int m0 = by * 128;
  const int n0 = bx * 64;
  const int wm = (wave >> 1) * 64;    // 0 or 64
  const int wn = (wave & 1) * 32;     // 0 or 32

  // staging: A 128 rows x 8 slots = 1024 slots (4/thread); B 512 (2/thread)
  auto stage = [&](int buf, int kc) {
#pragma unroll
    for (int j = 0; j < 4; j++) {
      int sidx = tid + 256*j;         // 0..1023
      int row = sidx >> 3;            // 0..127
      int gs = (sidx & 7) ^ (row & 7);
      gload_lds16(A + (size_t)(m0 + row)*K + kc + gs*8, As[buf] + sidx*8);
    }
#pragma unroll
    for (int j = 0; j < 2; j++) {
      int sidx = tid + 256*j;         // 0..511
      int row = sidx >> 3;            // 0..63
      int gs = (sidx & 7) ^ (row & 7);
      gload_lds16(Bt + (size_t)(n0 + row)*K + kc + gs*8, Bs[buf] + sidx*8);
    }
  };

  const int nt = K >> 6;              // K/64 (4 or 8)
  stage(0, 0);

  f32x4 acc[4][2] = {};
  int cur = 0;
  for (int t = 0; t < nt; t++) {
    if (t + 1 < nt) {
      stage(cur ^ 1, (t+1)*64);
      asm volatile("s_waitcnt vmcnt(6)" ::: "memory");   // current tile landed
    } else {
      asm volatile("s_waitcnt vmcnt(0)" ::: "memory");
    }
    __builtin_amdgcn_s_barrier();

    const unsigned short* as_ = As[cur];
    const unsigned short* bs_ = Bs[cur];
#pragma unroll
    for (int kh = 0; kh < 2; kh++) {
      bf16x8 af[4], bfv[2];
#pragma unroll
      for (int tt = 0; tt < 4; tt++) {
        int ra = wm + tt*16 + lm;
        af[tt] = *(const bf16x8*)(as_ + ra*64 + ((((kh<<2)|quad) ^ (ra & 7)) << 3));
      }
#pragma unroll
      for (int j = 0; j < 2; j++) {
        int rb = wn + j*16 + lm;
        bfv[j] = *(const bf16x8*)(bs_ + rb*64 + ((((kh<<2)|quad) ^ (rb & 7)) << 3));
      }
#pragma unroll
      for (int i = 0; i < 4; i++)
#pragma unroll
        for (int j = 0; j < 2; j++)
          acc[i][j] = __builtin_amdgcn_mfma_f32_16x16x32_bf16(af[i], bfv[j], acc[i][j], 0, 0, 0);
    }
    __builtin_amdgcn_s_barrier();     // all waves done reading cur before overwrite
    cur ^= 1;
  }

#pragma unroll
  for (int j = 0; j < 2; j++) {
    int col = n0 + wn + j*16 + lm;
    float bv = (bias2 && col >= splitN) ? bias2[col - splitN] : bias[col];
#pragma unroll
    for (int i = 0; i < 4; i++) {
      int r0 = m0 + wm + i*16 + quad*4;
#pragma unroll
      for (int e = 0; e < 4; e++) {
        int rr = r0 + e;
        float v = acc[i][j][e] + bv;
        if (EPI == 0) {
          if (out2 && col >= splitN) out2[(size_t)rr*ld2 + (col - splitN)] = f2bf(v);
          else                       out1[(size_t)rr*ld1 + col] = f2bf(v);
        } else if (EPI == 1) {
          out1[(size_t)rr*ld1 + col] = f2bf(fmaxf(v, 0.f));
        } else {
          size_t xi = (size_t)rr*256 + col;
          x_io[xi] += bf2f(gt[xi]) * v;
        }
      }
    }
  }
}

// =================================================================================
extern "C" void kernel_launch(void* const* d_in, const int* in_sizes, int n_in,
                              void* d_out, int out_size, void* d_ws, size_t ws_size,
                              hipStream_t stream)
{
  const float* x_in = (const float*)d_in[0];
  const float* pre  = (const float*)d_in[1];
  const float* cc   = (const float*)d_in[2];
  const int*   mask = (const int*)d_in[3];
  const float* wq = (const float*)d_in[4];   const float* bq = (const float*)d_in[5];
  const float* wk = (const float*)d_in[6];   const float* bk = (const float*)d_in[7];
  const float* wv = (const float*)d_in[8];   const float* bvz = (const float*)d_in[9];
  const float* wo = (const float*)d_in[10];  const float* bo = (const float*)d_in[11];
  const float* sa_w1 = (const float*)d_in[12]; const float* sa_b1 = (const float*)d_in[13];
  const float* sa_g1 = (const float*)d_in[14]; const float* sa_sb1 = (const float*)d_in[15];
  const float* sa_w2 = (const float*)d_in[16]; const float* sa_b2 = (const float*)d_in[17];
  const float* sa_g2 = (const float*)d_in[18]; const float* sa_sb2 = (const float*)d_in[19];
  const float* jrp_w = (const float*)d_in[20]; const float* jrp_b = (const float*)d_in[21];
  const float* dwp = (const float*)d_in[22]; const float* swp = (const float*)d_in[23];
  const float* cwp = (const float*)d_in[24]; const float* dsp = (const float*)d_in[25];
  const float* A_hat = (const float*)d_in[26];
  const float* g1w = (const float*)d_in[27]; const float* g1b = (const float*)d_in[28];
  const float* g2w = (const float*)d_in[29]; const float* g2b = (const float*)d_in[30];
  const float* n1g = (const float*)d_in[31]; const float* n1b = (const float*)d_in[32];
  const float* n2g = (const float*)d_in[33]; const float* n2b = (const float*)d_in[34];
  const float* ada1w = (const float*)d_in[35]; const float* ada1b = (const float*)d_in[36];
  const float* ada2w = (const float*)d_in[37]; const float* ada2b = (const float*)d_in[38];

  char* ws = (char*)d_ws;
  size_t off = 0;
  auto alloc = [&](size_t bytes)->char* {
    char* p = ws + off; off = (off + bytes + 255) & ~(size_t)255; return p;
  };

  // -------- fixed region: transposed weights (bf16) + Lm --------
  TJobs jobs;
  int ji = 0;
  auto addjob = [&](const float* src, unsigned short* dst, int Kd, int Nd) {
    jobs.j[ji].src = src; jobs.j[ji].dst = dst; jobs.j[ji].K = Kd; jobs.j[ji].N = Nd;
    ji++;
  };
  unsigned short *t_ada1[2], *t_qsa[2], *t_kv[2], *t_wo[2],
                 *t_sa2[2], *t_jrp[2], *t_g1[2], *t_g2[2], *t_ada2[2];
  for (int L = 0; L < 2; L++) {
    t_ada1[L] = (unsigned short*)alloc((size_t)768*256*2);
    addjob(ada1w + (size_t)L*256*768, t_ada1[L], 256, 768);
    t_qsa[L] = (unsigned short*)alloc((size_t)384*256*2);      // [wq^T ; sa_w1^T]
    addjob(wq + (size_t)L*65536, t_qsa[L], 256, 256);
    addjob(sa_w1 + (size_t)L*256*128, t_qsa[L] + 256*256, 256, 128);
    t_kv[L] = (unsigned short*)alloc((size_t)512*256*2);       // [wk^T ; wv^T]
    addjob(wk + (size_t)L*65536, t_kv[L], 256, 256);
    addjob(wv + (size_t)L*65536, t_kv[L] + 256*256, 256, 256);
    t_wo[L] = (unsigned short*)alloc((size_t)256*256*2);
    addjob(wo + (size_t)L*65536, t_wo[L], 256, 256);
    t_sa2[L] = (unsigned short*)alloc((size_t)64*128*2);
    addjob(sa_w2 + (size_t)L*128*64, t_sa2[L], 128, 64);
    t_jrp[L] = (unsigned short*)alloc((size_t)17*64*2);
    addjob(jrp_w + (size_t)L*64*17, t_jrp[L], 64, 17);
    t_g1[L] = (unsigned short*)alloc((size_t)512*256*2);
    addjob(g1w + (size_t)L*256*512, t_g1[L], 256, 512);
    t_g2[L] = (unsigned short*)alloc((size_t)256*512*2);
    addjob(g2w + (size_t)L*512*256, t_g2[L], 512, 256);
    t_ada2[L] = (unsigned short*)alloc((size_t)768*256*2);
    addjob(ada2w + (size_t)L*256*768, t_ada2[L], 256, 768);
  }
  float* lmbuf = (float*)alloc(2*289*4);
  size_t fixed_bytes = off;

  // -------- pick chunk size so scratch fits ws_size --------
  // per-row scratch: pre_bf 512 + silc 512 + xinb 512 + qbuf 512 + gtbuf 512
  //                + kvb 1024 + skel 68  = 3652 B
  int chunkB = BATCH;
  for (; chunkB > 256; chunkB >>= 1) {
    size_t R = (size_t)chunkB * NJ;
    if (fixed_bytes + R*3652 + 8*256 <= ws_size) break;
  }
  const size_t R = (size_t)chunkB * NJ;          // rows per chunk
  const int nchunks = BATCH / chunkB;

  unsigned short* pre_bf  = (unsigned short*)alloc(R*256*2);
  unsigned short* silc_bf = (unsigned short*)alloc(R*256*2);
  unsigned short* xinb    = (unsigned short*)alloc(R*256*2);   // also hosts jf1/jf2
  unsigned short* qbuf    = (unsigned short*)alloc(R*256*2);   // Q, then att (in place)
  unsigned short* gtbuf   = (unsigned short*)alloc(R*256*2);   // gate columns
  unsigned short* kvb     = (unsigned short*)alloc(R*512*2);   // sh|sc, then K|V, then g1-out
  float*          skelb   = (float*)alloc(R*NJ*4);

  unsigned short* jf1 = xinb;                 // rows x 128 (xinb dead when used)
  unsigned short* jf2 = xinb + R*128;         // rows x 64

  float* xout = (float*)d_out;
  hipMemcpyAsync(xout, x_in, (size_t)BATCH*NJ*256*4, hipMemcpyDeviceToDevice, stream);
  transpose_kernel<<<dim3(768, 22), 256, 0, stream>>>(jobs);
  lm_kernel<<<2, 64, 0, stream>>>(A_hat, lmbuf);

  const int gX = (int)(R/128);    // 128-row blocks (small gemm + main gemm y-dim)
  const int g4 = (int)(R/4);      // LN-style grids

  for (int ch = 0; ch < nchunks; ch++) {
    const size_t r0 = (size_t)ch * R;           // global row offset
    const float* pre_c = pre + r0*256;
    const float* cc_c  = cc + r0*256;
    const int* mask_c  = mask + (size_t)ch*chunkB*289;
    float* x_c = xout + r0*256;

    prep_kernel<<<g4, 256, 0, stream>>>(pre_c, cc_c, pre_bf, silc_bf);

    for (int L = 0; L < 2; L++) {
      // ---- sublayer 0: adaLN + skeleton-biased attention ----
      // ada1 fused N=768: cols 0-511 -> kvb (sh|sc, ld 512), cols 512-767 -> gtbuf
      gemm_lds_kernel<0><<<dim3(12,gX),256,0,stream>>>(silc_bf, t_ada1[L],
          ada1b + L*768, nullptr, kvb, 512, gtbuf, 256, 512, nullptr, nullptr, 256);
      lnmod_kernel<<<g4,256,0,stream>>>(x_c, kvb, n1g + L*256, n1b + L*256, xinb);
      // K|V fused N=512 -> kvb [R][512] (runs before qsa: jf1 aliases xinb)
      gemm_lds_kernel<0><<<dim3(8,gX),256,0,stream>>>(xinb, t_kv[L],
          bk + L*256, bvz + L*256, kvb, 512, nullptr, 0, 256, nullptr, nullptr, 256);
      // Q + sa1 fused N=384: cols 0-255 -> qbuf, cols 256-383 -> jf1
      gemm_lds_kernel<0><<<dim3(6,gX),256,0,stream>>>(pre_bf, t_qsa[L],
          bq + L*256, sa_b1 + L*128, qbuf, 256, jf1, 128, 256, nullptr, nullptr, 256);
      lnstd_relu_kernel<128><<<g4,256,0,stream>>>(jf1, sa_g1 + L*128, sa_sb1 + L*128);
      gemm_kernel<4,2,0><<<dim3(gX,1),256,0,stream>>>(jf1, t_sa2[L], sa_b2 + L*64, jf2, nullptr, nullptr, 64, 128);
      lnstd_relu_kernel<64><<<g4,256,0,stream>>>(jf2, sa_g2 + L*64, sa_sb2 + L*64);
      skel_kernel<<<(int)(R*NJ/256),256,0,stream>>>(jf2, t_jrp[L], jrp_b + L*17, dwp+L, swp+L, cwp+L, dsp+L, skelb);
      attn_kernel<<<chunkB,320,0,stream>>>(qbuf, kvb, skelb, mask_c, qbuf);
      gemm_lds_kernel<3><<<dim3(4,gX),256,0,stream>>>(qbuf, t_wo[L],
          bo + L*256, nullptr, nullptr, 0, nullptr, 0, 0, x_c, gtbuf, 256);
      // ---- sublayer 1: adaLN + GraphNet ----
      gemm_lds_kernel<0><<<dim3(12,gX),256,0,stream>>>(silc_bf, t_ada2[L],
          ada2b + L*768, nullptr, kvb, 512, gtbuf, 256, 512, nullptr, nullptr, 256);
      lnmod_kernel<<<g4,256,0,stream>>>(x_c, kvb, n2g + L*256, n2b + L*256, xinb);
      lmapply_kernel<256><<<chunkB,256,0,stream>>>(xinb, lmbuf + L*289);
      gemm_lds_kernel<1><<<dim3(8,gX),256,0,stream>>>(xinb, t_g1[L],
          g1b + L*512, nullptr, kvb, 512, nullptr, 0, 0, nullptr, nullptr, 256);
      lmapply_kernel<512><<<chunkB,256,0,stream>>>(kvb, lmbuf + L*289);
      gemm_lds_kernel<3><<<dim3(4,gX),256,0,stream>>>(kvb, t_g2[L],
          g2b + L*256, nullptr, nullptr, 0, nullptr, 0, 0, x_c, gtbuf, 512);
    }
  }
}

// Round 9
// 1523.811 us; speedup vs baseline: 1.2093x; 1.0063x over previous
//
#include <hip/hip_runtime.h>
#include <stdint.h>

// GraFormer forward, MI355X gfx950.
// x (residual) kept fp32 in d_out, updated in place by GEMM epilogues.
// All GEMM operands bf16 (MFMA 16x16x32), fp32 accumulate.
// R1-R3: LDS-staged GEMM + pipeline + XCD swizzle + fusions.
// R4/R5: attn d-split + block-per-batch-elem LDS staging.
// R6 (failed): 128KB single-shot -> 1 block/CU, occupancy 9%.
// R7: 64x64 tile -> 4 blocks/CU, MfmaUtil 12.6%. R8: 64x32 wave tile.
// R9: attn VALU diet: K/V converted bf16->f32 ONCE during LDS staging (the
//     hot loop paid ~32 extract ops per 16 FMAs, 2x over); mask folded into
//     staged skm/bm so the score is one FMA. LDS 17.4->34.8KB (4 blocks/CU).

#define BATCH 4096
#define NJ 17
#define NHEAD 8

typedef __bf16 bf16x8 __attribute__((ext_vector_type(8)));
typedef float f32x4 __attribute__((ext_vector_type(4)));

__device__ __forceinline__ float bf2f(unsigned short u){
  union { unsigned int i; float f; } v; v.i = ((unsigned int)u) << 16; return v.f;
}
__device__ __forceinline__ unsigned short f2bf(float f){
  union { float f; unsigned int i; } v; v.f = f;
  unsigned int i = v.i;
  return (unsigned short)((i + 0x7fffu + ((i >> 16) & 1u)) >> 16);
}
__device__ __forceinline__ float blo(unsigned int v){ union{unsigned int i;float f;}x; x.i=v<<16; return x.f; }
__device__ __forceinline__ float bhi(unsigned int v){ union{unsigned int i;float f;}x; x.i=v&0xffff0000u; return x.f; }

__device__ __forceinline__ void gload_lds16(const void* g, void* l) {
  __builtin_amdgcn_global_load_lds(
      (const __attribute__((address_space(1))) unsigned int*)g,
      (__attribute__((address_space(3))) unsigned int*)l, 16, 0, 0);
}

// ---------------- prep: pre_3d -> bf16, silu(c) -> bf16 (per chunk) ----------------
__global__ __launch_bounds__(256) void prep_kernel(
    const float* __restrict__ pre, const float* __restrict__ c,
    unsigned short* __restrict__ pre_bf, unsigned short* __restrict__ silc_bf)
{
  size_t i = (size_t)(blockIdx.x*256 + threadIdx.x)*4;
  float4 p = *(const float4*)(pre + i);
  float4 cv = *(const float4*)(c + i);
  float s0 = cv.x/(1.f+__expf(-cv.x));
  float s1 = cv.y/(1.f+__expf(-cv.y));
  float s2 = cv.z/(1.f+__expf(-cv.z));
  float s3 = cv.w/(1.f+__expf(-cv.w));
  uint2 po, so;
  po.x = (unsigned)f2bf(p.x) | ((unsigned)f2bf(p.y)<<16);
  po.y = (unsigned)f2bf(p.z) | ((unsigned)f2bf(p.w)<<16);
  so.x = (unsigned)f2bf(s0) | ((unsigned)f2bf(s1)<<16);
  so.y = (unsigned)f2bf(s2) | ((unsigned)f2bf(s3)<<16);
  *(uint2*)(pre_bf + i) = po;
  *(uint2*)(silc_bf + i) = so;
}

// ---------------- batched weight transpose+convert: dst[n*K+k] = bf16(src[k*N+n]) ----
struct TJob { const float* src; unsigned short* dst; int K; int N; };
struct TJobs { TJob j[22]; };

__global__ __launch_bounds__(256) void transpose_kernel(TJobs jobs)
{
  TJob jb = jobs.j[blockIdx.y];
  int total = jb.K * jb.N;
  int idx = blockIdx.x*256 + threadIdx.x;
  if (idx >= total) return;
  int n = idx / jb.K;
  int k = idx - n*jb.K;
  jb.dst[idx] = f2bf(jb.src[(size_t)k*jb.N + n]);
}

// ---------------- Lm = dh[:,None]*A*dh[None,:], dh=(colsum+1e-5)^-0.5 -----------
__global__ void lm_kernel(const float* __restrict__ A_hat, float* __restrict__ LmOut)
{
  int L = blockIdx.x;
  const float* a = A_hat + L*289;
  float* Lm = LmOut + L*289;
  __shared__ float dh[17];
  int t = threadIdx.x;
  if (t < 17) {
    float s = 0;
    for (int i = 0; i < 17; i++) s += a[i*17 + t];
    dh[t] = 1.0f/sqrtf(s + 1e-5f);
  }
  __syncthreads();
  for (int i = t; i < 289; i += 64) {
    int qq = i/17, jj = i - qq*17;
    Lm[i] = dh[qq]*a[i]*dh[jj];
  }
}

// ---- custom-LN (unbiased std, eps added to std) + adaLN modulate ----
// shsc: [rows, 512] bf16 (sh = cols 0-255, sc = cols 256-511)
__global__ __launch_bounds__(256) void lnmod_kernel(
    const float* __restrict__ x, const unsigned short* __restrict__ shsc,
    const float* __restrict__ g, const float* __restrict__ b,
    unsigned short* __restrict__ out)
{
  int row = blockIdx.x*4 + (threadIdx.x>>6);
  int lane = threadIdx.x & 63;
  const float4 v = *(const float4*)(x + (size_t)row*256 + lane*4);
  float s = v.x+v.y+v.z+v.w;
#pragma unroll
  for (int o=32;o;o>>=1) s += __shfl_down(s,o,64);
  float mu = __shfl(s,0,64) * (1.f/256.f);
  float d0=v.x-mu,d1=v.y-mu,d2=v.z-mu,d3=v.w-mu;
  float qq = d0*d0+d1*d1+d2*d2+d3*d3;
#pragma unroll
  for (int o=32;o;o>>=1) qq += __shfl_down(qq,o,64);
  qq = __shfl(qq,0,64);
  float rstd = 1.f/(sqrtf(qq*(1.f/255.f)) + 1e-6f);
  int c = lane*4;
  const float4 gv = *(const float4*)(g + c);
  const float4 bv = *(const float4*)(b + c);
  const uint2 shp = *(const uint2*)(shsc + (size_t)row*512 + c);
  const uint2 scp = *(const uint2*)(shsc + (size_t)row*512 + 256 + c);
  float o0 = (gv.x*d0*rstd + bv.x)*(1.f+blo(scp.x)) + blo(shp.x);
  float o1 = (gv.y*d1*rstd + bv.y)*(1.f+bhi(scp.x)) + bhi(shp.x);
  float o2 = (gv.z*d2*rstd + bv.z)*(1.f+blo(scp.y)) + blo(shp.y);
  float o3 = (gv.w*d3*rstd + bv.w)*(1.f+bhi(scp.y)) + bhi(shp.y);
  uint2 ov;
  ov.x = (unsigned)f2bf(o0) | ((unsigned)f2bf(o1)<<16);
  ov.y = (unsigned)f2bf(o2) | ((unsigned)f2bf(o3)<<16);
  *(uint2*)(out + (size_t)row*256 + c) = ov;
}

// ---------------- standard LN (biased var, eps in sqrt) + relu, in place, bf16 ----
template<int C>
__global__ __launch_bounds__(256) void lnstd_relu_kernel(
    unsigned short* __restrict__ io, const float* __restrict__ g, const float* __restrict__ b)
{
  constexpr int EPL = C/64;
  int row = blockIdx.x*4 + (threadIdx.x>>6);
  int lane = threadIdx.x & 63;
  unsigned short* rp = io + (size_t)row*C + lane*EPL;
  float v[EPL];
  if constexpr (EPL == 2) { unsigned int u = *(const unsigned int*)rp; v[0]=blo(u); v[1]=bhi(u); }
  else { v[0] = bf2f(rp[0]); }
  float s = 0;
#pragma unroll
  for (int e=0;e<EPL;e++) s += v[e];
#pragma unroll
  for (int o=32;o;o>>=1) s += __shfl_down(s,o,64);
  float mu = __shfl(s,0,64) * (1.f/C);
  float qq = 0;
#pragma unroll
  for (int e=0;e<EPL;e++){ float d=v[e]-mu; qq += d*d; }
#pragma unroll
  for (int o=32;o;o>>=1) qq += __shfl_down(qq,o,64);
  qq = __shfl(qq,0,64);
  float rstd = rsqrtf(qq*(1.f/C) + 1e-5f);
  unsigned short ov[EPL];
#pragma unroll
  for (int e=0;e<EPL;e++){
    int ccol = lane*EPL + e;
    float o = fmaxf(g[ccol]*(v[e]-mu)*rstd + b[ccol], 0.f);
    ov[e] = f2bf(o);
  }
  if constexpr (EPL==2){ *(unsigned int*)rp = (unsigned)ov[0] | ((unsigned)ov[1]<<16); }
  else rp[0] = ov[0];
}

// ---------------- skel = base_mask + sigmoid(jf2 @ jrp_w + jrp_b)*dyn_scale ------
__global__ __launch_bounds__(256) void skel_kernel(
    const unsigned short* __restrict__ jf2, const unsigned short* __restrict__ jrpt,
    const float* __restrict__ jrp_b,
    const float* __restrict__ dwp, const float* __restrict__ swp,
    const float* __restrict__ cwp, const float* __restrict__ dsp,
    float* __restrict__ skel)
{
  int gid = blockIdx.x*256 + threadIdx.x;
  int row = gid / 17;
  int k = gid - row*17;
  int q = row % 17;
  const uint4* a = (const uint4*)(jf2 + (size_t)row*64);
  const uint4* w = (const uint4*)(jrpt + k*64);
  float acc = jrp_b[k];
#pragma unroll
  for (int c = 0; c < 8; c++) {
    uint4 ua = a[c], uw = w[c];
    acc += blo(ua.x)*blo(uw.x) + bhi(ua.x)*bhi(uw.x)
         + blo(ua.y)*blo(uw.y) + bhi(ua.y)*bhi(uw.y)
         + blo(ua.z)*blo(uw.z) + bhi(ua.z)*bhi(uw.z)
         + blo(ua.w)*blo(uw.w) + bhi(ua.w)*bhi(uw.w);
  }
  float sig = 1.f/(1.f + __expf(-acc));
  float base = 1.f;
  const int dqa[16] = {0,1,2,0,4,5,0,7,8,9,8,11,12,8,14,15};
  const int dka[16] = {1,2,3,4,5,6,7,8,9,10,11,12,13,14,15,16};
#pragma unroll
  for (int t = 0; t < 16; t++) if (q==dqa[t] && k==dka[t]) base += dwp[0];
  const int s0a[6] = {1,2,3,11,12,13};
  const int s1a[6] = {4,5,6,14,15,16};
#pragma unroll
  for (int t = 0; t < 6; t++) if ((q==s0a[t]&&k==s1a[t])||(q==s1a[t]&&k==s0a[t])) base += swp[0];
  if (q==k) base += cwp[0];
  skel[gid] = base + sig*dsp[0];
}

// ---------------- attention: block per batch elem, f32 K/V in LDS ---------------
// KV global: [rows][512] bf16 (K cols 0-255, V cols 256-511). Staging converts
// to f32 ONCE; hot loop reads float4 (no per-use bf16 extraction -> ~half the
// VALU ops). mask folded into skm/bm: score = s*skm + bm (one FMA).
// 320 threads (5 waves); threads 0..271 active: pair (2t,2t+1) shares one
// (h,q), 16 dims each; partial QK dots combined via __shfl_xor(.,1).
__device__ __forceinline__ void load16f(const unsigned short* p, float* f){
  const uint4* p4 = (const uint4*)p;
#pragma unroll
  for (int c=0;c<2;c++){
    uint4 u=p4[c];
    f[c*8+0]=blo(u.x); f[c*8+1]=bhi(u.x); f[c*8+2]=blo(u.y); f[c*8+3]=bhi(u.y);
    f[c*8+4]=blo(u.z); f[c*8+5]=bhi(u.z); f[c*8+6]=blo(u.w); f[c*8+7]=bhi(u.w);
  }
}

__global__ __launch_bounds__(320) void attn_kernel(
    const unsigned short* Q, const unsigned short* __restrict__ KV,
    const float* __restrict__ skel,
    const int* __restrict__ mask, unsigned short* att)
{
  __shared__ float kvs[17*512];    // 34816 B (f32)
  __shared__ float skm[289];       // sk or 0
  __shared__ float bm[289];        // 0 or -1e9
  const int b = blockIdx.x;
  const int tid = threadIdx.x;

  const uint4* src = (const uint4*)(KV + (size_t)b*17*512);
  for (int i = tid; i < 1088; i += 320) {
    uint4 u = src[i];
    float4 f0 = { blo(u.x), bhi(u.x), blo(u.y), bhi(u.y) };
    float4 f1 = { blo(u.z), bhi(u.z), blo(u.w), bhi(u.w) };
    *(float4*)(kvs + 8*i)     = f0;
    *(float4*)(kvs + 8*i + 4) = f1;
  }
  const float* skb = skel + (size_t)b*289;
  const int* mkb = mask + (size_t)b*289;
  for (int i = tid; i < 289; i += 320) {
    int m = mkb[i];
    skm[i] = m ? skb[i] : 0.f;
    bm[i]  = m ? 0.f : -1e9f;
  }
  __syncthreads();
  if (tid >= 272) return;

  const int t2 = tid >> 1;            // (h,q) work item, 0..135
  const int dh = tid & 1;             // d-half
  const int h = t2 / 17;
  const int q = t2 - h*17;
  const int col = h*32 + dh*16;       // element offset within a KV row
  size_t rq = ((size_t)(b*17+q))*256 + col;
  float qv[16];
  load16f(Q + rq, qv);

  float p[17];
  float mx = -3e38f;
#pragma unroll
  for (int k = 0; k < 17; k++) {
    const float* kp = kvs + k*512 + col;
    float s = 0;
#pragma unroll
    for (int c = 0; c < 4; c++) {
      float4 u = *(const float4*)(kp + c*4);
      s += qv[c*4+0]*u.x + qv[c*4+1]*u.y + qv[c*4+2]*u.z + qv[c*4+3]*u.w;
    }
    s += __shfl_xor(s, 1, 64);        // combine the two d-halves
    s *= 0.17677669529663687f;        // 1/sqrt(32)
    float gvl = s*skm[q*17+k] + bm[q*17+k];
    p[k] = gvl;
    mx = fmaxf(mx, gvl);
  }
  float sum = 0;
#pragma unroll
  for (int k = 0; k < 17; k++){ p[k] = __expf(p[k]-mx); sum += p[k]; }
  float inv = 1.f/sum;
  float acc[16];
#pragma unroll
  for (int d=0; d<16; d++) acc[d]=0;
#pragma unroll
  for (int k = 0; k < 17; k++) {
    float pk = p[k]*inv;
    const float* vp = kvs + k*512 + 256 + col;
#pragma unroll
    for (int c=0;c<4;c++){
      float4 u = *(const float4*)(vp + c*4);
      acc[c*4+0] += pk*u.x; acc[c*4+1] += pk*u.y;
      acc[c*4+2] += pk*u.z; acc[c*4+3] += pk*u.w;
    }
  }
  uint4 o[2];
#pragma unroll
  for (int c=0;c<2;c++){
    o[c].x = (unsigned)f2bf(acc[c*8+0]) | ((unsigned)f2bf(acc[c*8+1])<<16);
    o[c].y = (unsigned)f2bf(acc[c*8+2]) | ((unsigned)f2bf(acc[c*8+3])<<16);
    o[c].z = (unsigned)f2bf(acc[c*8+4]) | ((unsigned)f2bf(acc[c*8+5])<<16);
    o[c].w = (unsigned)f2bf(acc[c*8+6]) | ((unsigned)f2bf(acc[c*8+7])<<16);
  }
  uint4* op = (uint4*)(att + rq);
  op[0] = o[0]; op[1] = o[1];
}

// ---------------- Lm @ y per batch-elem, in place (17xD), D = 256 or 512 ---------
template<int D>
__global__ __launch_bounds__(256) void lmapply_kernel(
    unsigned short* __restrict__ io, const float* __restrict__ Lm)
{
  __shared__ unsigned short ys[17*D];
  __shared__ float lms[289];
  int b = blockIdx.x;
  int tid = threadIdx.x;
  unsigned short* base = io + (size_t)b*17*D;
  constexpr int CH = 17*D/8;
  for (int i = tid; i < CH; i += 256) ((uint4*)ys)[i] = ((const uint4*)base)[i];
  for (int i = tid; i < 289; i += 256) lms[i] = Lm[i];
  __syncthreads();
#pragma unroll
  for (int c0 = 0; c0 < D; c0 += 256) {
    int c = c0 + tid;
    float yv[17];
#pragma unroll
    for (int j = 0; j < 17; j++) yv[j] = bf2f(ys[j*D + c]);
#pragma unroll
    for (int qi = 0; qi < 17; qi++) {
      float a = 0;
#pragma unroll
      for (int j = 0; j < 17; j++) a += lms[qi*17+j]*yv[j];
      base[qi*D + c] = f2bf(a);
    }
  }
}

// ---------------- small GEMM (register-direct, kept for N=64): ------------------
template<int TM, int TN, int EPI>
__global__ __launch_bounds__(256) void gemm_kernel(
    const unsigned short* __restrict__ A, const unsigned short* __restrict__ Bt,
    const float* __restrict__ bias, unsigned short* __restrict__ outbf,
    float* __restrict__ x_io, const unsigned short* __restrict__ gt,
    int N, int K)
{
  int lane = threadIdx.x & 63;
  int wave = threadIdx.x >> 6;
  int lm = lane & 15, quad = lane >> 4;
  int wm0 = blockIdx.x*(2*TM*16) + (wave>>1)*(TM*16);
  int wn0 = blockIdx.y*(2*TN*16) + (wave&1)*(TN*16);
  const unsigned short* pa[TM];
  const unsigned short* pb[TN];
#pragma unroll
  for (int t=0;t<TM;t++) pa[t] = A + (size_t)(wm0 + t*16 + lm)*K + quad*8;
#pragma unroll
  for (int t=0;t<TN;t++) pb[t] = Bt + (size_t)(wn0 + t*16 + lm)*K + quad*8;
  f32x4 acc[TM][TN] = {};
  for (int kc = 0; kc < K; kc += 32) {
    bf16x8 af[TM], bfv[TN];
#pragma unroll
    for (int t=0;t<TM;t++) af[t] = *(const bf16x8*)(pa[t] + kc);
#pragma unroll
    for (int t=0;t<TN;t++) bfv[t] = *(const bf16x8*)(pb[t] + kc);
#pragma unroll
    for (int i=0;i<TM;i++)
#pragma unroll
      for (int j=0;j<TN;j++)
        acc[i][j] = __builtin_amdgcn_mfma_f32_16x16x32_bf16(af[i], bfv[j], acc[i][j], 0, 0, 0);
  }
#pragma unroll
  for (int j=0;j<TN;j++) {
    int col = wn0 + j*16 + lm;
    float bv = bias[col];
#pragma unroll
    for (int i=0;i<TM;i++) {
      int r0 = wm0 + i*16 + quad*4;
#pragma unroll
      for (int e=0;e<4;e++) {
        int rr = r0 + e;
        float v = acc[i][j][e] + bv;
        if (EPI == 0) {
          outbf[(size_t)rr*N + col] = f2bf(v);
        } else if (EPI == 1) {
          outbf[(size_t)rr*N + col] = f2bf(fmaxf(v, 0.f));
        } else {
          size_t xi = (size_t)rr*N + col;
          x_io[xi] += bf2f(gt[(size_t)rr*256 + col]) * v;
        }
      }
    }
  }
}

// ---------------- main GEMM: 128x64 block, 64x32 wave tile, BK=64 dbuf ----------
// grid = (N/64, M/128), XCD-bijective remap (A-panel L2 reuse).
// 256 thr = 4 waves (2x2 of 64x32 tiles), acc[4][2] = 32 AGPR.
// LDS: As[2][128][64] 32KB + Bs[2][64][64] 16KB = 48KB -> 3 blocks/CU
// (12 waves/CU). Per BK tile per wave: 12 b128 reads -> 16 MFMA.
// Counted vmcnt(6): stage next tile (6 gload_lds/thread) while computing.
// Swizzle: physical 16B slot p of row r (128B rows, 8 slots) holds global
// slot p^(r&7); applied on global source, same XOR on ds_read -> 0 conflicts.
// EPI: 0 = store bf16 (optional split at splitN -> out2), 1 = relu store,
//      3 = x_io += bf2f(gt)*val (N=256 fixed).
template<int EPI>
__global__ __launch_bounds__(256, 3) void gemm_lds_kernel(
    const unsigned short* __restrict__ A, const unsigned short* __restrict__ Bt,
    const float* __restrict__ bias, const float* __restrict__ bias2,
    unsigned short* __restrict__ out1, int ld1,
    unsigned short* __restrict__ out2, int ld2, int splitN,
    float* __restrict__ x_io, const unsigned short* __restrict__ gt,
    int K)
{
  __shared__ unsigned short As[2][128*64];   // 16 KB per buf
  __shared__ unsigned short Bs[2][64*64];    //  8 KB per buf
  const int tid = threadIdx.x;
  const int lane = tid & 63;
  const int wave = tid >> 6;
  const int lm = lane & 15, quad = lane >> 4;

  // bijective XCD remap: flat -> wg such that each XCD owns a contiguous range
  const int gx = gridDim.x;
  const int nwg = gx * (int)gridDim.y;
  int flat = (int)blockIdx.y * gx + (int)blockIdx.x;
  int xcd = flat & 7, idx = flat >> 3;
  int qd = nwg >> 3, rm = nwg & 7;
  int wg = (xcd < rm ? xcd*(qd+1) : rm*(qd+1) + (xcd-rm)*qd) + idx;
  int by = wg / gx, bx = wg - by*gx;
  const int m0 = by * 128;
  const int n0 = bx * 64;
  const int wm = (wave >> 1) * 64;    // 0 or 64
  const int wn = (wave & 1) * 32;     // 0 or 32

  // staging: A 128 rows x 8 slots = 1024 slots (4/thread); B 512 (2/thread)
  auto stage = [&](int buf, int kc) {
#pragma unroll
    for (int j = 0; j < 4; j++) {
      int sidx = tid + 256*j;         // 0..1023
      int row = sidx >> 3;            // 0..127
      int gs = (sidx & 7) ^ (row & 7);
      gload_lds16(A + (size_t)(m0 + row)*K + kc + gs*8, As[buf] + sidx*8);
    }
#pragma unroll
    for (int j = 0; j < 2; j++) {
      int sidx = tid + 256*j;         // 0..511
      int row = sidx >> 3;            // 0..63
      int gs = (sidx & 7) ^ (row & 7);
      gload_lds16(Bt + (size_t)(n0 + row)*K + kc + gs*8, Bs[buf] + sidx*8);
    }
  };

  const int nt = K >> 6;              // K/64 (4 or 8)
  stage(0, 0);

  f32x4 acc[4][2] = {};
  int cur = 0;
  for (int t = 0; t < nt; t++) {
    if (t + 1 < nt) {
      stage(cur ^ 1, (t+1)*64);
      asm volatile("s_waitcnt vmcnt(6)" ::: "memory");   // current tile landed
    } else {
      asm volatile("s_waitcnt vmcnt(0)" ::: "memory");
    }
    __builtin_amdgcn_s_barrier();

    const unsigned short* as_ = As[cur];
    const unsigned short* bs_ = Bs[cur];
#pragma unroll
    for (int kh = 0; kh < 2; kh++) {
      bf16x8 af[4], bfv[2];
#pragma unroll
      for (int tt = 0; tt < 4; tt++) {
        int ra = wm + tt*16 + lm;
        af[tt] = *(const bf16x8*)(as_ + ra*64 + ((((kh<<2)|quad) ^ (ra & 7)) << 3));
      }
#pragma unroll
      for (int j = 0; j < 2; j++) {
        int rb = wn + j*16 + lm;
        bfv[j] = *(const bf16x8*)(bs_ + rb*64 + ((((kh<<2)|quad) ^ (rb & 7)) << 3));
      }
#pragma unroll
      for (int i = 0; i < 4; i++)
#pragma unroll
        for (int j = 0; j < 2; j++)
          acc[i][j] = __builtin_amdgcn_mfma_f32_16x16x32_bf16(af[i], bfv[j], acc[i][j], 0, 0, 0);
    }
    __builtin_amdgcn_s_barrier();     // all waves done reading cur before overwrite
    cur ^= 1;
  }

#pragma unroll
  for (int j = 0; j < 2; j++) {
    int col = n0 + wn + j*16 + lm;
    float bv = (bias2 && col >= splitN) ? bias2[col - splitN] : bias[col];
#pragma unroll
    for (int i = 0; i < 4; i++) {
      int r0 = m0 + wm + i*16 + quad*4;
#pragma unroll
      for (int e = 0; e < 4; e++) {
        int rr = r0 + e;
        float v = acc[i][j][e] + bv;
        if (EPI == 0) {
          if (out2 && col >= splitN) out2[(size_t)rr*ld2 + (col - splitN)] = f2bf(v);
          else                       out1[(size_t)rr*ld1 + col] = f2bf(v);
        } else if (EPI == 1) {
          out1[(size_t)rr*ld1 + col] = f2bf(fmaxf(v, 0.f));
        } else {
          size_t xi = (size_t)rr*256 + col;
          x_io[xi] += bf2f(gt[xi]) * v;
        }
      }
    }
  }
}

// =================================================================================
extern "C" void kernel_launch(void* const* d_in, const int* in_sizes, int n_in,
                              void* d_out, int out_size, void* d_ws, size_t ws_size,
                              hipStream_t stream)
{
  const float* x_in = (const float*)d_in[0];
  const float* pre  = (const float*)d_in[1];
  const float* cc   = (const float*)d_in[2];
  const int*   mask = (const int*)d_in[3];
  const float* wq = (const float*)d_in[4];   const float* bq = (const float*)d_in[5];
  const float* wk = (const float*)d_in[6];   const float* bk = (const float*)d_in[7];
  const float* wv = (const float*)d_in[8];   const float* bvz = (const float*)d_in[9];
  const float* wo = (const float*)d_in[10];  const float* bo = (const float*)d_in[11];
  const float* sa_w1 = (const float*)d_in[12]; const float* sa_b1 = (const float*)d_in[13];
  const float* sa_g1 = (const float*)d_in[14]; const float* sa_sb1 = (const float*)d_in[15];
  const float* sa_w2 = (const float*)d_in[16]; const float* sa_b2 = (const float*)d_in[17];
  const float* sa_g2 = (const float*)d_in[18]; const float* sa_sb2 = (const float*)d_in[19];
  const float* jrp_w = (const float*)d_in[20]; const float* jrp_b = (const float*)d_in[21];
  const float* dwp = (const float*)d_in[22]; const float* swp = (const float*)d_in[23];
  const float* cwp = (const float*)d_in[24]; const float* dsp = (const float*)d_in[25];
  const float* A_hat = (const float*)d_in[26];
  const float* g1w = (const float*)d_in[27]; const float* g1b = (const float*)d_in[28];
  const float* g2w = (const float*)d_in[29]; const float* g2b = (const float*)d_in[30];
  const float* n1g = (const float*)d_in[31]; const float* n1b = (const float*)d_in[32];
  const float* n2g = (const float*)d_in[33]; const float* n2b = (const float*)d_in[34];
  const float* ada1w = (const float*)d_in[35]; const float* ada1b = (const float*)d_in[36];
  const float* ada2w = (const float*)d_in[37]; const float* ada2b = (const float*)d_in[38];

  char* ws = (char*)d_ws;
  size_t off = 0;
  auto alloc = [&](size_t bytes)->char* {
    char* p = ws + off; off = (off + bytes + 255) & ~(size_t)255; return p;
  };

  // -------- fixed region: transposed weights (bf16) + Lm --------
  TJobs jobs;
  int ji = 0;
  auto addjob = [&](const float* src, unsigned short* dst, int Kd, int Nd) {
    jobs.j[ji].src = src; jobs.j[ji].dst = dst; jobs.j[ji].K = Kd; jobs.j[ji].N = Nd;
    ji++;
  };
  unsigned short *t_ada1[2], *t_qsa[2], *t_kv[2], *t_wo[2],
                 *t_sa2[2], *t_jrp[2], *t_g1[2], *t_g2[2], *t_ada2[2];
  for (int L = 0; L < 2; L++) {
    t_ada1[L] = (unsigned short*)alloc((size_t)768*256*2);
    addjob(ada1w + (size_t)L*256*768, t_ada1[L], 256, 768);
    t_qsa[L] = (unsigned short*)alloc((size_t)384*256*2);      // [wq^T ; sa_w1^T]
    addjob(wq + (size_t)L*65536, t_qsa[L], 256, 256);
    addjob(sa_w1 + (size_t)L*256*128, t_qsa[L] + 256*256, 256, 128);
    t_kv[L] = (unsigned short*)alloc((size_t)512*256*2);       // [wk^T ; wv^T]
    addjob(wk + (size_t)L*65536, t_kv[L], 256, 256);
    addjob(wv + (size_t)L*65536, t_kv[L] + 256*256, 256, 256);
    t_wo[L] = (unsigned short*)alloc((size_t)256*256*2);
    addjob(wo + (size_t)L*65536, t_wo[L], 256, 256);
    t_sa2[L] = (unsigned short*)alloc((size_t)64*128*2);
    addjob(sa_w2 + (size_t)L*128*64, t_sa2[L], 128, 64);
    t_jrp[L] = (unsigned short*)alloc((size_t)17*64*2);
    addjob(jrp_w + (size_t)L*64*17, t_jrp[L], 64, 17);
    t_g1[L] = (unsigned short*)alloc((size_t)512*256*2);
    addjob(g1w + (size_t)L*256*512, t_g1[L], 256, 512);
    t_g2[L] = (unsigned short*)alloc((size_t)256*512*2);
    addjob(g2w + (size_t)L*512*256, t_g2[L], 512, 256);
    t_ada2[L] = (unsigned short*)alloc((size_t)768*256*2);
    addjob(ada2w + (size_t)L*256*768, t_ada2[L], 256, 768);
  }
  float* lmbuf = (float*)alloc(2*289*4);
  size_t fixed_bytes = off;

  // -------- pick chunk size so scratch fits ws_size --------
  // per-row scratch: pre_bf 512 + silc 512 + xinb 512 + qbuf 512 + gtbuf 512
  //                + kvb 1024 + skel 68  = 3652 B
  int chunkB = BATCH;
  for (; chunkB > 256; chunkB >>= 1) {
    size_t R = (size_t)chunkB * NJ;
    if (fixed_bytes + R*3652 + 8*256 <= ws_size) break;
  }
  const size_t R = (size_t)chunkB * NJ;          // rows per chunk
  const int nchunks = BATCH / chunkB;

  unsigned short* pre_bf  = (unsigned short*)alloc(R*256*2);
  unsigned short* silc_bf = (unsigned short*)alloc(R*256*2);
  unsigned short* xinb    = (unsigned short*)alloc(R*256*2);   // also hosts jf1/jf2
  unsigned short* qbuf    = (unsigned short*)alloc(R*256*2);   // Q, then att (in place)
  unsigned short* gtbuf   = (unsigned short*)alloc(R*256*2);   // gate columns
  unsigned short* kvb     = (unsigned short*)alloc(R*512*2);   // sh|sc, then K|V, then g1-out
  float*          skelb   = (float*)alloc(R*NJ*4);

  unsigned short* jf1 = xinb;                 // rows x 128 (xinb dead when used)
  unsigned short* jf2 = xinb + R*128;         // rows x 64

  float* xout = (float*)d_out;
  hipMemcpyAsync(xout, x_in, (size_t)BATCH*NJ*256*4, hipMemcpyDeviceToDevice, stream);
  transpose_kernel<<<dim3(768, 22), 256, 0, stream>>>(jobs);
  lm_kernel<<<2, 64, 0, stream>>>(A_hat, lmbuf);

  const int gX = (int)(R/128);    // 128-row blocks (small gemm + main gemm y-dim)
  const int g4 = (int)(R/4);      // LN-style grids

  for (int ch = 0; ch < nchunks; ch++) {
    const size_t r0 = (size_t)ch * R;           // global row offset
    const float* pre_c = pre + r0*256;
    const float* cc_c  = cc + r0*256;
    const int* mask_c  = mask + (size_t)ch*chunkB*289;
    float* x_c = xout + r0*256;

    prep_kernel<<<g4, 256, 0, stream>>>(pre_c, cc_c, pre_bf, silc_bf);

    for (int L = 0; L < 2; L++) {
      // ---- sublayer 0: adaLN + skeleton-biased attention ----
      // ada1 fused N=768: cols 0-511 -> kvb (sh|sc, ld 512), cols 512-767 -> gtbuf
      gemm_lds_kernel<0><<<dim3(12,gX),256,0,stream>>>(silc_bf, t_ada1[L],
          ada1b + L*768, nullptr, kvb, 512, gtbuf, 256, 512, nullptr, nullptr, 256);
      lnmod_kernel<<<g4,256,0,stream>>>(x_c, kvb, n1g + L*256, n1b + L*256, xinb);
      // K|V fused N=512 -> kvb [R][512] (runs before qsa: jf1 aliases xinb)
      gemm_lds_kernel<0><<<dim3(8,gX),256,0,stream>>>(xinb, t_kv[L],
          bk + L*256, bvz + L*256, kvb, 512, nullptr, 0, 256, nullptr, nullptr, 256);
      // Q + sa1 fused N=384: cols 0-255 -> qbuf, cols 256-383 -> jf1
      gemm_lds_kernel<0><<<dim3(6,gX),256,0,stream>>>(pre_bf, t_qsa[L],
          bq + L*256, sa_b1 + L*128, qbuf, 256, jf1, 128, 256, nullptr, nullptr, 256);
      lnstd_relu_kernel<128><<<g4,256,0,stream>>>(jf1, sa_g1 + L*128, sa_sb1 + L*128);
      gemm_kernel<4,2,0><<<dim3(gX,1),256,0,stream>>>(jf1, t_sa2[L], sa_b2 + L*64, jf2, nullptr, nullptr, 64, 128);
      lnstd_relu_kernel<64><<<g4,256,0,stream>>>(jf2, sa_g2 + L*64, sa_sb2 + L*64);
      skel_kernel<<<(int)(R*NJ/256),256,0,stream>>>(jf2, t_jrp[L], jrp_b + L*17, dwp+L, swp+L, cwp+L, dsp+L, skelb);
      attn_kernel<<<chunkB,320,0,stream>>>(qbuf, kvb, skelb, mask_c, qbuf);
      gemm_lds_kernel<3><<<dim3(4,gX),256,0,stream>>>(qbuf, t_wo[L],
          bo + L*256, nullptr, nullptr, 0, nullptr, 0, 0, x_c, gtbuf, 256);
      // ---- sublayer 1: adaLN + GraphNet ----
      gemm_lds_kernel<0><<<dim3(12,gX),256,0,stream>>>(silc_bf, t_ada2[L],
          ada2b + L*768, nullptr, kvb, 512, gtbuf, 256, 512, nullptr, nullptr, 256);
      lnmod_kernel<<<g4,256,0,stream>>>(x_c, kvb, n2g + L*256, n2b + L*256, xinb);
      lmapply_kernel<256><<<chunkB,256,0,stream>>>(xinb, lmbuf + L*289);
      gemm_lds_kernel<1><<<dim3(8,gX),256,0,stream>>>(xinb, t_g1[L],
          g1b + L*512, nullptr, kvb, 512, nullptr, 0, 0, nullptr, nullptr, 256);
      lmapply_kernel<512><<<chunkB,256,0,stream>>>(kvb, lmbuf + L*289);
      gemm_lds_kernel<3><<<dim3(4,gX),256,0,stream>>>(kvb, t_g2[L],
          g2b + L*256, nullptr, nullptr, 0, nullptr, 0, 0, x_c, gtbuf, 512);
    }
  }
}